// Round 1
// baseline (1297.048 us; speedup 1.0000x reference)
//
#include <hip/hip_runtime.h>
#include <math.h>

#define HIDDEN   1024
#define D_INNER  2048
#define NSTATE   16
#define DT_RANK  64
#define D_CONV   4
#define BATCH    2
#define SEQ      2048
#define T_TOK    (BATCH * SEQ)       /* 4096 tokens */
#define XDBL     (DT_RANK + 2 * NSTATE)   /* 96 */

__device__ __forceinline__ float silu_f(float x) {
    return x / (1.0f + __expf(-x));
}
__device__ __forceinline__ float softplus_f(float x) {
    return fmaxf(x, 0.0f) + log1pf(__expf(-fabsf(x)));
}

/* ---------------- RMSNorm: one block per token row ---------------- */
__global__ __launch_bounds__(256) void rmsnorm_kernel(
        const float* __restrict__ x, const float* __restrict__ w,
        float* __restrict__ xn) {
    int row = blockIdx.x;
    const float4* xr = (const float4*)(x + (size_t)row * HIDDEN);
    float4 v = xr[threadIdx.x];                  /* 256 thr * 4 = 1024 */
    float ss = v.x*v.x + v.y*v.y + v.z*v.z + v.w*v.w;
    #pragma unroll
    for (int off = 32; off; off >>= 1) ss += __shfl_down(ss, off);
    __shared__ float wsum[4];
    if ((threadIdx.x & 63) == 0) wsum[threadIdx.x >> 6] = ss;
    __syncthreads();
    float tot = wsum[0] + wsum[1] + wsum[2] + wsum[3];
    float scale = rsqrtf(tot / (float)HIDDEN + 1e-5f);
    float4 wv = ((const float4*)w)[threadIdx.x];
    float4 o;
    o.x = v.x * scale * wv.x;
    o.y = v.y * scale * wv.y;
    o.z = v.z * scale * wv.z;
    o.w = v.w * scale * wv.w;
    ((float4*)(xn + (size_t)row * HIDDEN))[threadIdx.x] = o;
}

/* ---------------- Generic fp32 GEMM: C[M,N] = A[M,K] @ W[N,K]^T ----
   EPI 0: plain store to C0
   EPI 1: split columns: col < splitN -> C0, else C1 (col-splitN)
   EPI 2: softplus(v + bias[col]) -> C0
   EPI 3: v + resid[row,col] -> C0
-------------------------------------------------------------------- */
#define BM 64
#define BN 64
#define BK 16

template<int EPI>
__global__ __launch_bounds__(256) void gemm_kernel(
        const float* __restrict__ A, int lda,
        const float* __restrict__ W,
        float* __restrict__ C0, int ldc0,
        float* __restrict__ C1, int ldc1, int splitN,
        const float* __restrict__ bias,
        const float* __restrict__ resid, int ldr,
        int M, int N, int K) {
    __shared__ float As[BK][BM + 4];
    __shared__ float Bs[BK][BN + 4];
    const int m0 = blockIdx.y * BM;
    const int n0 = blockIdx.x * BN;
    const int t  = threadIdx.x;
    const int lr = t >> 2;            /* 0..63 row within tile        */
    const int lk = (t & 3) << 2;      /* 0,4,8,12 k within tile       */
    const int tm = (t & 15) << 2;     /* 0..60 thread micro-tile row  */
    const int tn = (t >> 4) << 2;     /* 0..60 thread micro-tile col  */
    float acc[4][4] = {};
    for (int k0 = 0; k0 < K; k0 += BK) {
        float4 av = *(const float4*)(A + (size_t)(m0 + lr) * lda + k0 + lk);
        float4 bv = make_float4(0.f, 0.f, 0.f, 0.f);
        int wrow = n0 + lr;
        if (wrow < N) bv = *(const float4*)(W + (size_t)wrow * K + k0 + lk);
        __syncthreads();
        As[lk + 0][lr] = av.x; As[lk + 1][lr] = av.y;
        As[lk + 2][lr] = av.z; As[lk + 3][lr] = av.w;
        Bs[lk + 0][lr] = bv.x; Bs[lk + 1][lr] = bv.y;
        Bs[lk + 2][lr] = bv.z; Bs[lk + 3][lr] = bv.w;
        __syncthreads();
        #pragma unroll
        for (int k = 0; k < BK; ++k) {
            float4 a = *(const float4*)&As[k][tm];
            float4 b = *(const float4*)&Bs[k][tn];
            acc[0][0] += a.x*b.x; acc[0][1] += a.x*b.y; acc[0][2] += a.x*b.z; acc[0][3] += a.x*b.w;
            acc[1][0] += a.y*b.x; acc[1][1] += a.y*b.y; acc[1][2] += a.y*b.z; acc[1][3] += a.y*b.w;
            acc[2][0] += a.z*b.x; acc[2][1] += a.z*b.y; acc[2][2] += a.z*b.z; acc[2][3] += a.z*b.w;
            acc[3][0] += a.w*b.x; acc[3][1] += a.w*b.y; acc[3][2] += a.w*b.z; acc[3][3] += a.w*b.w;
        }
    }
    #pragma unroll
    for (int i = 0; i < 4; ++i) {
        int row = m0 + tm + i;
        #pragma unroll
        for (int j = 0; j < 4; ++j) {
            int col = n0 + tn + j;
            if (col >= N) continue;
            float v = acc[i][j];
            if (EPI == 0) {
                C0[(size_t)row * ldc0 + col] = v;
            } else if (EPI == 1) {
                if (col < splitN) C0[(size_t)row * ldc0 + col] = v;
                else              C1[(size_t)row * ldc1 + (col - splitN)] = v;
            } else if (EPI == 2) {
                C0[(size_t)row * ldc0 + col] = softplus_f(v + bias[col]);
            } else {
                C0[(size_t)row * ldc0 + col] = v + resid[(size_t)row * ldr + col];
            }
        }
    }
}

/* ---------------- causal depthwise conv (d_conv=4) + SiLU ---------------- */
__global__ __launch_bounds__(256) void conv_silu_kernel(
        const float* __restrict__ xi, const float* __restrict__ w,
        const float* __restrict__ b, float* __restrict__ xc) {
    size_t i = (size_t)blockIdx.x * 256 + threadIdx.x;   /* over T_TOK*D_INNER */
    int d = (int)(i & (D_INNER - 1));
    int t = (int)(i >> 11);          /* /2048 */
    int s = t & (SEQ - 1);
    float4 wv = ((const float4*)w)[d];
    float acc = b[d];
    if (s >= 3) acc += wv.x * xi[i - 3 * D_INNER];
    if (s >= 2) acc += wv.y * xi[i - 2 * D_INNER];
    if (s >= 1) acc += wv.z * xi[i - 1 * D_INNER];
    acc += wv.w * xi[i];
    xc[i] = silu_f(acc);
}

/* ---------------- selective scan ----------------
   one block = 16 channels (same batch b), 16 lanes per channel (one per n).
   LDS-staged chunks of 64 timesteps.                                   */
#define SCHUNK 64
__global__ __launch_bounds__(256) void scan_kernel(
        const float* __restrict__ xc, const float* __restrict__ delta,
        const float* __restrict__ xdbl, const float* __restrict__ A_log,
        const float* __restrict__ Dp, float* __restrict__ y) {
    __shared__ float sB[SCHUNK][NSTATE + 1];
    __shared__ float sC[SCHUNK][NSTATE + 1];
    __shared__ float sD[SCHUNK][NSTATE + 1];
    __shared__ float sU[SCHUNK][NSTATE + 1];
    __shared__ float sY[SCHUNK][NSTATE + 1];
    const int bid = blockIdx.x;                 /* 0..255 */
    const int b   = bid / (D_INNER / 16);
    const int d0  = (bid % (D_INNER / 16)) * 16;
    const int t   = threadIdx.x;
    const int g   = t >> 4;     /* channel within block */
    const int n   = t & 15;     /* state index          */
    const int d   = d0 + g;
    const float Adn = -__expf(A_log[d * NSTATE + n]);
    const float Dd  = Dp[d];
    float h = 0.0f;
    for (int s0 = 0; s0 < SEQ; s0 += SCHUNK) {
        __syncthreads();
        #pragma unroll
        for (int q = 0; q < 4; ++q) {
            int r = (t >> 4) + (q << 4);
            size_t row = (size_t)(b * SEQ + s0 + r);
            sB[r][n] = xdbl[row * XDBL + DT_RANK + n];
            sC[r][n] = xdbl[row * XDBL + DT_RANK + NSTATE + n];
            sD[r][n] = delta[row * D_INNER + d0 + n];
            sU[r][n] = xc[row * D_INNER + d0 + n];
        }
        __syncthreads();
        for (int i = 0; i < SCHUNK; ++i) {
            float dl = sD[i][g];
            float u  = sU[i][g];
            float Bn = sB[i][n];
            float Cn = sC[i][n];
            float dA = __expf(dl * Adn);
            h = fmaf(dA, h, dl * Bn * u);
            float yp = h * Cn;
            yp += __shfl_xor(yp, 1);
            yp += __shfl_xor(yp, 2);
            yp += __shfl_xor(yp, 4);
            yp += __shfl_xor(yp, 8);
            if (n == 0) sY[i][g] = fmaf(u, Dd, yp);
        }
        __syncthreads();
        #pragma unroll
        for (int q = 0; q < 4; ++q) {
            int r = (t >> 4) + (q << 4);
            size_t row = (size_t)(b * SEQ + s0 + r);
            y[row * D_INNER + d0 + n] = sY[r][n];
        }
    }
}

/* ---------------- y *= silu(res) ---------------- */
__global__ __launch_bounds__(256) void gate_kernel(
        float* __restrict__ y, const float* __restrict__ res) {
    size_t i = (size_t)blockIdx.x * 256 + threadIdx.x;   /* float4 index */
    float4 yv = ((const float4*)y)[i];
    float4 rv = ((const float4*)res)[i];
    yv.x *= silu_f(rv.x);
    yv.y *= silu_f(rv.y);
    yv.z *= silu_f(rv.z);
    yv.w *= silu_f(rv.w);
    ((float4*)y)[i] = yv;
}

extern "C" void kernel_launch(void* const* d_in, const int* in_sizes, int n_in,
                              void* d_out, int out_size, void* d_ws, size_t ws_size,
                              hipStream_t stream) {
    const float* x         = (const float*)d_in[0];
    const float* norm_w    = (const float*)d_in[1];
    const float* in_proj_w = (const float*)d_in[2];
    const float* conv_w    = (const float*)d_in[3];
    const float* conv_b    = (const float*)d_in[4];
    const float* x_proj_w  = (const float*)d_in[5];
    const float* dt_proj_w = (const float*)d_in[6];
    const float* dt_proj_b = (const float*)d_in[7];
    const float* A_log     = (const float*)d_in[8];
    const float* Dp        = (const float*)d_in[9];
    const float* out_proj_w= (const float*)d_in[10];
    float* out = (float*)d_out;
    float* ws  = (float*)d_ws;

    const size_t TD = (size_t)T_TOK * D_INNER;      /* 8M floats */
    const size_t TH = (size_t)T_TOK * HIDDEN;       /* 4M floats */
    float* xi    = ws;                              /* [0, 8M)    */
    float* xn    = ws + TD;                         /* [8M, 12M)  */
    float* res   = xn + TH;                         /* [12M, 20M) */
    float* xc    = res + TD;                        /* [20M, 28M) */
    float* xdbl  = xc + TD;                         /* [28M, ~28.4M) */
    float* delta = xdbl + (size_t)T_TOK * XDBL;     /* 8M         */
    float* yb    = xi;                              /* reuse: xi dead after conv */

    /* 1. RMSNorm */
    rmsnorm_kernel<<<T_TOK, 256, 0, stream>>>(x, norm_w, xn);

    /* 2. in_proj: [4096,1024] @ [4096,1024]^T -> xi | res */
    {
        dim3 g(2 * D_INNER / BN, T_TOK / BM);
        gemm_kernel<1><<<g, 256, 0, stream>>>(
            xn, HIDDEN, in_proj_w,
            xi, D_INNER, res, D_INNER, D_INNER,
            nullptr, nullptr, 0,
            T_TOK, 2 * D_INNER, HIDDEN);
    }

    /* 3. causal depthwise conv + SiLU */
    conv_silu_kernel<<<(int)(TD / 256), 256, 0, stream>>>(xi, conv_w, conv_b, xc);

    /* 4. x_proj: [4096,2048] @ [96,2048]^T -> xdbl */
    {
        dim3 g((XDBL + BN - 1) / BN, T_TOK / BM);
        gemm_kernel<0><<<g, 256, 0, stream>>>(
            xc, D_INNER, x_proj_w,
            xdbl, XDBL, nullptr, 0, 0,
            nullptr, nullptr, 0,
            T_TOK, XDBL, D_INNER);
    }

    /* 5. dt_proj + bias + softplus -> delta */
    {
        dim3 g(D_INNER / BN, T_TOK / BM);
        gemm_kernel<2><<<g, 256, 0, stream>>>(
            xdbl, XDBL, dt_proj_w,
            delta, D_INNER, nullptr, 0, 0,
            dt_proj_b, nullptr, 0,
            T_TOK, D_INNER, DT_RANK);
    }

    /* 6. selective scan -> yb */
    scan_kernel<<<BATCH * D_INNER / 16, 256, 0, stream>>>(
        xc, delta, xdbl, A_log, Dp, yb);

    /* 7. y *= silu(res) */
    gate_kernel<<<(int)(TD / 4 / 256), 256, 0, stream>>>(yb, res);

    /* 8. out_proj + residual: [4096,2048] @ [1024,2048]^T + x -> out */
    {
        dim3 g(HIDDEN / BN, T_TOK / BM);
        gemm_kernel<3><<<g, 256, 0, stream>>>(
            yb, D_INNER, out_proj_w,
            out, HIDDEN, nullptr, 0, 0,
            nullptr, x, HIDDEN,
            T_TOK, HIDDEN, D_INNER);
    }
}

// Round 2
// 641.898 us; speedup vs baseline: 2.0206x; 2.0206x over previous
//
#include <hip/hip_runtime.h>
#include <math.h>

#define HIDDEN   1024
#define D_INNER  2048
#define NSTATE   16
#define DT_RANK  64
#define BATCH    2
#define SEQ      2048
#define T_TOK    (BATCH * SEQ)            /* 4096 tokens */
#define XDBL     (DT_RANK + 2 * NSTATE)   /* 96 */
#define NCH      32                       /* scan chunks */
#define CHL      (SEQ / NCH)              /* 64 steps per chunk */
#define BDN      (BATCH * D_INNER * NSTATE) /* 65536 */

typedef float f32x4   __attribute__((ext_vector_type(4)));
typedef short bf16x8  __attribute__((ext_vector_type(8)));
typedef short short4v __attribute__((ext_vector_type(4)));

__device__ __forceinline__ float silu_f(float x) { return x / (1.0f + __expf(-x)); }
__device__ __forceinline__ float softplus_f(float x) {
    return fmaxf(x, 0.0f) + log1pf(__expf(-fabsf(x)));
}
__device__ __forceinline__ unsigned short f2bf(float x) {
    unsigned int u = __float_as_uint(x);
    u += 0x7fffu + ((u >> 16) & 1u);           /* RNE */
    return (unsigned short)(u >> 16);
}
__device__ __forceinline__ float bf2f(unsigned short h) {
    return __uint_as_float(((unsigned int)h) << 16);
}

/* ---- weight split-pack: W[rows,K] fp32 -> Wp[rows,3K] bf16 = [hi|lo|hi] ---- */
__global__ __launch_bounds__(256) void wpack_kernel(
        const float* __restrict__ w, unsigned short* __restrict__ wp, int K) {
    int i = blockIdx.x * 256 + threadIdx.x;          /* over rows*K/4, exact grid */
    int kq = K >> 2;
    int row = i / kq;
    int c = (i - row * kq) << 2;
    float4 v = *(const float4*)(w + (size_t)row * K + c);
    short4v hi, lo;
    hi.x = f2bf(v.x); hi.y = f2bf(v.y); hi.z = f2bf(v.z); hi.w = f2bf(v.w);
    lo.x = f2bf(v.x - bf2f(hi.x)); lo.y = f2bf(v.y - bf2f(hi.y));
    lo.z = f2bf(v.z - bf2f(hi.z)); lo.w = f2bf(v.w - bf2f(hi.w));
    size_t b0 = (size_t)row * (3 * K) + c;
    *(short4v*)(wp + b0)         = hi;
    *(short4v*)(wp + b0 + K)     = lo;
    *(short4v*)(wp + b0 + 2 * K) = hi;
}

/* ---- RMSNorm fused with activation split-pack: x[row,1024] -> xn_p[row,3072]=[hi|hi|lo] ---- */
__global__ __launch_bounds__(256) void rmsnorm_pack_kernel(
        const float* __restrict__ x, const float* __restrict__ w,
        unsigned short* __restrict__ xn_p) {
    int row = blockIdx.x;
    float4 v = ((const float4*)(x + (size_t)row * HIDDEN))[threadIdx.x];
    float ss = v.x*v.x + v.y*v.y + v.z*v.z + v.w*v.w;
    #pragma unroll
    for (int off = 32; off; off >>= 1) ss += __shfl_down(ss, off);
    __shared__ float wsum[4];
    if ((threadIdx.x & 63) == 0) wsum[threadIdx.x >> 6] = ss;
    __syncthreads();
    float scale = rsqrtf((wsum[0] + wsum[1] + wsum[2] + wsum[3]) / (float)HIDDEN + 1e-5f);
    float4 wv = ((const float4*)w)[threadIdx.x];
    float o0 = v.x * scale * wv.x, o1 = v.y * scale * wv.y;
    float o2 = v.z * scale * wv.z, o3 = v.w * scale * wv.w;
    short4v hi, lo;
    hi.x = f2bf(o0); hi.y = f2bf(o1); hi.z = f2bf(o2); hi.w = f2bf(o3);
    lo.x = f2bf(o0 - bf2f(hi.x)); lo.y = f2bf(o1 - bf2f(hi.y));
    lo.z = f2bf(o2 - bf2f(hi.z)); lo.w = f2bf(o3 - bf2f(hi.w));
    size_t b0 = (size_t)row * (3 * HIDDEN) + threadIdx.x * 4;
    *(short4v*)&xn_p[b0]              = hi;
    *(short4v*)&xn_p[b0 + HIDDEN]     = hi;
    *(short4v*)&xn_p[b0 + 2 * HIDDEN] = lo;
}

/* ---- bf16 MFMA GEMM, m97 structure: 128x128 tile, BK=32, 4 waves ----
   C[M,N] = Ap[M,Kp] @ Wp[N,Kp]^T  (both bf16 row-major, Kp = 3K packed)
   EPI 0: col<splitN -> C0 else C1 (both stride ldout)
   EPI 1: C0 = acc + resid (stride ldout)                                */
template<int EPI>
__global__ __launch_bounds__(256) void mgemm_kernel(
        const unsigned short* __restrict__ Ap, const unsigned short* __restrict__ Wp,
        int Kp, float* __restrict__ C0, float* __restrict__ C1, int splitN,
        const float* __restrict__ resid, int ldout) {
    __shared__ short As[128 * 32];
    __shared__ short Bs[128 * 32];
    const int t = threadIdx.x;
    const int w = t >> 6, l = t & 63;
    const int m0 = blockIdx.y * 128, n0 = blockIdx.x * 128;
    const int wr = (w >> 1) * 64, wc = (w & 1) * 64;
    const int lrow = l & 15, lk8 = (l >> 4) * 8;
    f32x4 acc[4][4];
    #pragma unroll
    for (int m = 0; m < 4; ++m)
        #pragma unroll
        for (int n = 0; n < 4; ++n) {
            acc[m][n].x = 0.f; acc[m][n].y = 0.f; acc[m][n].z = 0.f; acc[m][n].w = 0.f;
        }
    const unsigned short* ga = Ap + (size_t)(m0 + (t >> 2)) * Kp + (t & 3) * 8;
    const unsigned short* gb = Wp + (size_t)(n0 + (t >> 2)) * Kp + (t & 3) * 8;
    char* lA = (char*)As + w * 1024;
    char* lB = (char*)Bs + w * 1024;
    for (int k0 = 0; k0 < Kp; k0 += 32) {
        __syncthreads();
        __builtin_amdgcn_global_load_lds(
            (const __attribute__((address_space(1))) unsigned int*)(ga + k0),
            (__attribute__((address_space(3))) unsigned int*)lA, 16, 0, 0);
        __builtin_amdgcn_global_load_lds(
            (const __attribute__((address_space(1))) unsigned int*)(ga + (size_t)64 * Kp + k0),
            (__attribute__((address_space(3))) unsigned int*)(lA + 4096), 16, 0, 0);
        __builtin_amdgcn_global_load_lds(
            (const __attribute__((address_space(1))) unsigned int*)(gb + k0),
            (__attribute__((address_space(3))) unsigned int*)lB, 16, 0, 0);
        __builtin_amdgcn_global_load_lds(
            (const __attribute__((address_space(1))) unsigned int*)(gb + (size_t)64 * Kp + k0),
            (__attribute__((address_space(3))) unsigned int*)(lB + 4096), 16, 0, 0);
        __syncthreads();
        bf16x8 af[4], bfr[4];
        #pragma unroll
        for (int m = 0; m < 4; ++m)
            af[m] = *(const bf16x8*)&As[(wr + m * 16 + lrow) * 32 + lk8];
        #pragma unroll
        for (int n = 0; n < 4; ++n)
            bfr[n] = *(const bf16x8*)&Bs[(wc + n * 16 + lrow) * 32 + lk8];
        #pragma unroll
        for (int m = 0; m < 4; ++m)
            #pragma unroll
            for (int n = 0; n < 4; ++n)
                acc[m][n] = __builtin_amdgcn_mfma_f32_16x16x32_bf16(
                    af[m], bfr[n], acc[m][n], 0, 0, 0);
    }
    #pragma unroll
    for (int m = 0; m < 4; ++m) {
        #pragma unroll
        for (int n = 0; n < 4; ++n) {
            #pragma unroll
            for (int j = 0; j < 4; ++j) {
                int row = m0 + wr + m * 16 + (l >> 4) * 4 + j;
                int col = n0 + wc + n * 16 + (l & 15);
                float v = acc[m][n][j];
                if (EPI == 0) {
                    if (col < splitN) C0[(size_t)row * ldout + col] = v;
                    else              C1[(size_t)row * ldout + (col - splitN)] = v;
                } else {
                    C0[(size_t)row * ldout + col] = v + resid[(size_t)row * ldout + col];
                }
            }
        }
    }
}

/* ---- fp32 GEMM for the small projections ----
   EPI 0: plain store; EPI 2: softplus(v + bias[col])                     */
#define BM 64
#define BN 64
#define BK 16
template<int EPI>
__global__ __launch_bounds__(256) void gemm_kernel(
        const float* __restrict__ A, int lda,
        const float* __restrict__ W,
        float* __restrict__ C0, int ldc0,
        const float* __restrict__ bias,
        int M, int N, int K) {
    __shared__ float As[BK][BM + 4];
    __shared__ float Bs[BK][BN + 4];
    const int m0 = blockIdx.y * BM;
    const int n0 = blockIdx.x * BN;
    const int t  = threadIdx.x;
    const int lr = t >> 2;
    const int lk = (t & 3) << 2;
    const int tm = (t & 15) << 2;
    const int tn = (t >> 4) << 2;
    float acc[4][4] = {};
    for (int k0 = 0; k0 < K; k0 += BK) {
        float4 av = *(const float4*)(A + (size_t)(m0 + lr) * lda + k0 + lk);
        float4 bv = make_float4(0.f, 0.f, 0.f, 0.f);
        int wrow = n0 + lr;
        if (wrow < N) bv = *(const float4*)(W + (size_t)wrow * K + k0 + lk);
        __syncthreads();
        As[lk + 0][lr] = av.x; As[lk + 1][lr] = av.y;
        As[lk + 2][lr] = av.z; As[lk + 3][lr] = av.w;
        Bs[lk + 0][lr] = bv.x; Bs[lk + 1][lr] = bv.y;
        Bs[lk + 2][lr] = bv.z; Bs[lk + 3][lr] = bv.w;
        __syncthreads();
        #pragma unroll
        for (int k = 0; k < BK; ++k) {
            float4 a = *(const float4*)&As[k][tm];
            float4 b = *(const float4*)&Bs[k][tn];
            acc[0][0] += a.x*b.x; acc[0][1] += a.x*b.y; acc[0][2] += a.x*b.z; acc[0][3] += a.x*b.w;
            acc[1][0] += a.y*b.x; acc[1][1] += a.y*b.y; acc[1][2] += a.y*b.z; acc[1][3] += a.y*b.w;
            acc[2][0] += a.z*b.x; acc[2][1] += a.z*b.y; acc[2][2] += a.z*b.z; acc[2][3] += a.z*b.w;
            acc[3][0] += a.w*b.x; acc[3][1] += a.w*b.y; acc[3][2] += a.w*b.z; acc[3][3] += a.w*b.w;
        }
    }
    #pragma unroll
    for (int i = 0; i < 4; ++i) {
        int row = m0 + tm + i;
        #pragma unroll
        for (int j = 0; j < 4; ++j) {
            int col = n0 + tn + j;
            if (col >= N) continue;
            float v = acc[i][j];
            if (EPI == 0) C0[(size_t)row * ldc0 + col] = v;
            else          C0[(size_t)row * ldc0 + col] = softplus_f(v + bias[col]);
        }
    }
}

/* ---- causal depthwise conv (d_conv=4) + SiLU ---- */
__global__ __launch_bounds__(256) void conv_silu_kernel(
        const float* __restrict__ xi, const float* __restrict__ w,
        const float* __restrict__ b, float* __restrict__ xc) {
    size_t i = (size_t)blockIdx.x * 256 + threadIdx.x;
    int d = (int)(i & (D_INNER - 1));
    int tt = (int)(i >> 11);
    int s = tt & (SEQ - 1);
    float4 wv = ((const float4*)w)[d];
    float acc = b[d];
    if (s >= 3) acc += wv.x * xi[i - 3 * D_INNER];
    if (s >= 2) acc += wv.y * xi[i - 2 * D_INNER];
    if (s >= 1) acc += wv.z * xi[i - 1 * D_INNER];
    acc += wv.w * xi[i];
    xc[i] = silu_f(acc);
}

/* ---- scan pass A: per-chunk summaries (P = prod dA, hpart = zero-state h) ---- */
__global__ __launch_bounds__(256) void scanA_kernel(
        const float* __restrict__ xc, const float* __restrict__ delta,
        const float* __restrict__ xdbl, const float* __restrict__ A_log,
        float* __restrict__ hpart, float* __restrict__ Pp) {
    __shared__ float sB[CHL][NSTATE + 1];
    __shared__ float sD[CHL][NSTATE + 1];
    __shared__ float sU[CHL][NSTATE + 1];
    const int bid = blockIdx.x;
    const int chunk = bid & (NCH - 1);
    const int rest  = bid >> 5;
    const int b  = rest >> 7;
    const int d0 = (rest & 127) << 4;
    const int t = threadIdx.x;
    const int g = t >> 4, n = t & 15;
    const float Adn = -__expf(A_log[(d0 + g) * NSTATE + n]);
    #pragma unroll
    for (int q = 0; q < 4; ++q) {
        int r = (t >> 4) + (q << 4);
        size_t row = (size_t)(b * SEQ + chunk * CHL + r);
        sB[r][n] = xdbl[row * XDBL + DT_RANK + n];
        sD[r][n] = delta[row * D_INNER + d0 + n];
        sU[r][n] = xc[row * D_INNER + d0 + n];
    }
    __syncthreads();
    float h = 0.f, P = 1.f;
    for (int i = 0; i < CHL; ++i) {
        float dl = sD[i][g], u = sU[i][g], Bn = sB[i][n];
        float dA = __expf(dl * Adn);
        h = fmaf(dA, h, dl * Bn * u);
        P *= dA;
    }
    int idx = (b * D_INNER + d0 + g) * NSTATE + n;
    hpart[(size_t)chunk * BDN + idx] = h;
    Pp[(size_t)chunk * BDN + idx]    = P;
}

/* ---- scan pass B: scan chunk summaries -> h_start per chunk ---- */
__global__ __launch_bounds__(256) void scanB_kernel(
        const float* __restrict__ hpart, const float* __restrict__ Pp,
        float* __restrict__ hstart) {
    int idx = blockIdx.x * 256 + threadIdx.x;
    float h = 0.f;
    for (int c = 0; c < NCH; ++c) {
        hstart[(size_t)c * BDN + idx] = h;
        h = fmaf(Pp[(size_t)c * BDN + idx], h, hpart[(size_t)c * BDN + idx]);
    }
}

/* ---- scan pass C: replay chunk with true h_start, fused gate + split-pack ---- */
__global__ __launch_bounds__(256) void scanC_kernel(
        const float* __restrict__ xc, const float* __restrict__ delta,
        const float* __restrict__ xdbl, const float* __restrict__ A_log,
        const float* __restrict__ Dp, const float* __restrict__ hstart,
        const float* __restrict__ res, unsigned short* __restrict__ y_p) {
    __shared__ float sB[CHL][NSTATE + 1];
    __shared__ float sC[CHL][NSTATE + 1];
    __shared__ float sD[CHL][NSTATE + 1];
    __shared__ float sU[CHL][NSTATE + 1];
    __shared__ float sY[CHL][NSTATE + 1];
    const int bid = blockIdx.x;
    const int chunk = bid & (NCH - 1);
    const int rest  = bid >> 5;
    const int b  = rest >> 7;
    const int d0 = (rest & 127) << 4;
    const int t = threadIdx.x;
    const int g = t >> 4, n = t & 15;
    const float Adn = -__expf(A_log[(d0 + g) * NSTATE + n]);
    const float Dd  = Dp[d0 + g];
    #pragma unroll
    for (int q = 0; q < 4; ++q) {
        int r = (t >> 4) + (q << 4);
        size_t row = (size_t)(b * SEQ + chunk * CHL + r);
        sB[r][n] = xdbl[row * XDBL + DT_RANK + n];
        sC[r][n] = xdbl[row * XDBL + DT_RANK + NSTATE + n];
        sD[r][n] = delta[row * D_INNER + d0 + n];
        sU[r][n] = xc[row * D_INNER + d0 + n];
    }
    __syncthreads();
    int idx = (b * D_INNER + d0 + g) * NSTATE + n;
    float h = hstart[(size_t)chunk * BDN + idx];
    for (int i = 0; i < CHL; ++i) {
        float dl = sD[i][g], u = sU[i][g], Bn = sB[i][n], Cn = sC[i][n];
        float dA = __expf(dl * Adn);
        h = fmaf(dA, h, dl * Bn * u);
        float yp = h * Cn;
        yp += __shfl_xor(yp, 1);
        yp += __shfl_xor(yp, 2);
        yp += __shfl_xor(yp, 4);
        yp += __shfl_xor(yp, 8);
        if (n == 0) sY[i][g] = fmaf(u, Dd, yp);
    }
    __syncthreads();
    #pragma unroll
    for (int q = 0; q < 4; ++q) {
        int r = (t >> 4) + (q << 4);
        size_t row = (size_t)(b * SEQ + chunk * CHL + r);
        float yv = sY[r][n];
        float rv = res[row * D_INNER + d0 + n];
        float gv = yv * silu_f(rv);
        unsigned short hi = f2bf(gv);
        unsigned short lo = f2bf(gv - bf2f(hi));
        size_t o = row * (size_t)(3 * D_INNER) + d0 + n;
        y_p[o]               = hi;
        y_p[o + D_INNER]     = hi;
        y_p[o + 2 * D_INNER] = lo;
    }
}

extern "C" void kernel_launch(void* const* d_in, const int* in_sizes, int n_in,
                              void* d_out, int out_size, void* d_ws, size_t ws_size,
                              hipStream_t stream) {
    const float* x         = (const float*)d_in[0];
    const float* norm_w    = (const float*)d_in[1];
    const float* in_proj_w = (const float*)d_in[2];
    const float* conv_w    = (const float*)d_in[3];
    const float* conv_b    = (const float*)d_in[4];
    const float* x_proj_w  = (const float*)d_in[5];
    const float* dt_proj_w = (const float*)d_in[6];
    const float* dt_proj_b = (const float*)d_in[7];
    const float* A_log     = (const float*)d_in[8];
    const float* Dp        = (const float*)d_in[9];
    const float* out_proj_w= (const float*)d_in[10];
    float* out = (float*)d_out;
    float* ws  = (float*)d_ws;

    const size_t M8 = (size_t)T_TOK * D_INNER;          /* 8388608 */
    float* res   = ws;                                   /* 8M  */
    float* xc    = res + M8;                             /* 8M  */
    float* delta = xc + M8;                              /* 8M  */
    float* xdbl  = delta + M8;                           /* 393216 */
    unsigned short* xn_p   = (unsigned short*)(xdbl + (size_t)T_TOK * XDBL); /* 4096x3072 */
    unsigned short* w_in_p = xn_p + (size_t)4096 * 3072;                     /* 4096x3072 */
    unsigned short* w_out_p= w_in_p + (size_t)4096 * 3072;                   /* 1024x6144 */
    unsigned short* y_p    = xn_p;             /* alias: xn_p+w_in_p dead after in_proj */
    float* xi    = (float*)(w_out_p + (size_t)1024 * 6144);                  /* 8M */
    float* hpart = xi;                         /* alias: xi dead after conv */
    float* Pp    = xi + (size_t)BDN * NCH;
    float* hstart= Pp + (size_t)BDN * NCH;

    /* weight packs (every launch; cheap, memory-bound) */
    wpack_kernel<<<4096, 256, 0, stream>>>(in_proj_w,  w_in_p,  HIDDEN);
    wpack_kernel<<<2048, 256, 0, stream>>>(out_proj_w, w_out_p, D_INNER);

    /* 1. RMSNorm + pack */
    rmsnorm_pack_kernel<<<T_TOK, 256, 0, stream>>>(x, norm_w, xn_p);

    /* 2. in_proj (MFMA split-bf16): [4096,3072]@[4096,3072]^T -> xi | res */
    {
        dim3 g(4096 / 128, T_TOK / 128);
        mgemm_kernel<0><<<g, 256, 0, stream>>>(xn_p, w_in_p, 3 * HIDDEN,
                                               xi, res, D_INNER, nullptr, D_INNER);
    }

    /* 3. conv + SiLU */
    conv_silu_kernel<<<(int)(M8 / 256), 256, 0, stream>>>(xi, conv_w, conv_b, xc);

    /* 4. x_proj (fp32): [4096,2048]@[96,2048]^T */
    {
        dim3 g((XDBL + BN - 1) / BN, T_TOK / BM);
        gemm_kernel<0><<<g, 256, 0, stream>>>(xc, D_INNER, x_proj_w, xdbl, XDBL,
                                              nullptr, T_TOK, XDBL, D_INNER);
    }

    /* 5. dt_proj + softplus (fp32) */
    {
        dim3 g(D_INNER / BN, T_TOK / BM);
        gemm_kernel<2><<<g, 256, 0, stream>>>(xdbl, XDBL, dt_proj_w, delta, D_INNER,
                                              dt_proj_b, T_TOK, D_INNER, DT_RANK);
    }

    /* 6. selective scan: chunked 2-pass */
    scanA_kernel<<<BATCH * (D_INNER / 16) * NCH, 256, 0, stream>>>(
        xc, delta, xdbl, A_log, hpart, Pp);
    scanB_kernel<<<BDN / 256, 256, 0, stream>>>(hpart, Pp, hstart);
    scanC_kernel<<<BATCH * (D_INNER / 16) * NCH, 256, 0, stream>>>(
        xc, delta, xdbl, A_log, Dp, hstart, res, y_p);

    /* 7. out_proj (MFMA split-bf16) + residual */
    {
        dim3 g(HIDDEN / 128, T_TOK / 128);
        mgemm_kernel<1><<<g, 256, 0, stream>>>(y_p, w_out_p, 3 * D_INNER,
                                               out, nullptr, 0, x, HIDDEN);
    }
}

// Round 3
// 561.715 us; speedup vs baseline: 2.3091x; 1.1427x over previous
//
#include <hip/hip_runtime.h>
#include <math.h>

#define HIDDEN   1024
#define D_INNER  2048
#define NSTATE   16
#define DT_RANK  64
#define BATCH    2
#define SEQ      2048
#define T_TOK    (BATCH * SEQ)            /* 4096 tokens */
#define XDBL     (DT_RANK + 2 * NSTATE)   /* 96 */
#define NCH      32                       /* scan chunks */
#define CHL      (SEQ / NCH)              /* 64 steps per chunk */
#define BDN      (BATCH * D_INNER * NSTATE) /* 65536 */

typedef float f32x4   __attribute__((ext_vector_type(4)));
typedef short bf16x8  __attribute__((ext_vector_type(8)));
typedef short short4v __attribute__((ext_vector_type(4)));

__device__ __forceinline__ float silu_f(float x) { return x / (1.0f + __expf(-x)); }
__device__ __forceinline__ float softplus_f(float x) {
    return fmaxf(x, 0.0f) + log1pf(__expf(-fabsf(x)));
}
__device__ __forceinline__ unsigned short f2bf(float x) {
    unsigned int u = __float_as_uint(x);
    u += 0x7fffu + ((u >> 16) & 1u);           /* RNE */
    return (unsigned short)(u >> 16);
}
__device__ __forceinline__ float bf2f(unsigned short h) {
    return __uint_as_float(((unsigned int)h) << 16);
}

/* ---- weight split-pack: W[rows,K] fp32 -> Wp[rows,3K] bf16 = [hi|lo|hi] ---- */
__global__ __launch_bounds__(256) void wpack_kernel(
        const float* __restrict__ w, unsigned short* __restrict__ wp, int K) {
    int i = blockIdx.x * 256 + threadIdx.x;
    int kq = K >> 2;
    int row = i / kq;
    int c = (i - row * kq) << 2;
    float4 v = *(const float4*)(w + (size_t)row * K + c);
    short4v hi, lo;
    hi.x = f2bf(v.x); hi.y = f2bf(v.y); hi.z = f2bf(v.z); hi.w = f2bf(v.w);
    lo.x = f2bf(v.x - bf2f(hi.x)); lo.y = f2bf(v.y - bf2f(hi.y));
    lo.z = f2bf(v.z - bf2f(hi.z)); lo.w = f2bf(v.w - bf2f(hi.w));
    size_t b0 = (size_t)row * (3 * K) + c;
    *(short4v*)(wp + b0)         = hi;
    *(short4v*)(wp + b0 + K)     = lo;
    *(short4v*)(wp + b0 + 2 * K) = hi;
}

/* ---- RMSNorm fused with split-pack: x[row,1024] -> xn_p[row,3072]=[hi|hi|lo] ---- */
__global__ __launch_bounds__(256) void rmsnorm_pack_kernel(
        const float* __restrict__ x, const float* __restrict__ w,
        unsigned short* __restrict__ xn_p) {
    int row = blockIdx.x;
    float4 v = ((const float4*)(x + (size_t)row * HIDDEN))[threadIdx.x];
    float ss = v.x*v.x + v.y*v.y + v.z*v.z + v.w*v.w;
    #pragma unroll
    for (int off = 32; off; off >>= 1) ss += __shfl_down(ss, off);
    __shared__ float wsum[4];
    if ((threadIdx.x & 63) == 0) wsum[threadIdx.x >> 6] = ss;
    __syncthreads();
    float scale = rsqrtf((wsum[0] + wsum[1] + wsum[2] + wsum[3]) / (float)HIDDEN + 1e-5f);
    float4 wv = ((const float4*)w)[threadIdx.x];
    float o0 = v.x * scale * wv.x, o1 = v.y * scale * wv.y;
    float o2 = v.z * scale * wv.z, o3 = v.w * scale * wv.w;
    short4v hi, lo;
    hi.x = f2bf(o0); hi.y = f2bf(o1); hi.z = f2bf(o2); hi.w = f2bf(o3);
    lo.x = f2bf(o0 - bf2f(hi.x)); lo.y = f2bf(o1 - bf2f(hi.y));
    lo.z = f2bf(o2 - bf2f(hi.z)); lo.w = f2bf(o3 - bf2f(hi.w));
    size_t b0 = (size_t)row * (3 * HIDDEN) + threadIdx.x * 4;
    *(short4v*)&xn_p[b0]              = hi;
    *(short4v*)&xn_p[b0 + HIDDEN]     = hi;
    *(short4v*)&xn_p[b0 + 2 * HIDDEN] = lo;
}

/* ---- bf16 MFMA GEMM (m97 structure) + XCD-aware block swizzle ----
   C[M,N] = Ap[M,Kp] @ Wp[N,Kp]^T
   EPI 0: col<splitN -> C0 else C1; EPI 1: C0 = acc + resid            */
template<int EPI>
__global__ __launch_bounds__(256) void mgemm_kernel(
        const unsigned short* __restrict__ Ap, const unsigned short* __restrict__ Wp,
        int Kp, float* __restrict__ C0, float* __restrict__ C1, int splitN,
        const float* __restrict__ resid, int ldout) {
    __shared__ short As[128 * 32];
    __shared__ short Bs[128 * 32];
    const int t = threadIdx.x;
    const int w = t >> 6, l = t & 63;
    /* bijective XCD swizzle (nwg % 8 == 0 for all our grids) */
    int lin = blockIdx.y * gridDim.x + blockIdx.x;
    int nwg = gridDim.x * gridDim.y;
    int q = nwg >> 3;
    int swz = (lin & 7) * q + (lin >> 3);
    const int m0 = (swz / (int)gridDim.x) * 128;
    const int n0 = (swz % (int)gridDim.x) * 128;
    const int wr = (w >> 1) * 64, wc = (w & 1) * 64;
    const int lrow = l & 15, lk8 = (l >> 4) * 8;
    f32x4 acc[4][4];
    #pragma unroll
    for (int m = 0; m < 4; ++m)
        #pragma unroll
        for (int n = 0; n < 4; ++n) {
            acc[m][n].x = 0.f; acc[m][n].y = 0.f; acc[m][n].z = 0.f; acc[m][n].w = 0.f;
        }
    const unsigned short* ga = Ap + (size_t)(m0 + (t >> 2)) * Kp + (t & 3) * 8;
    const unsigned short* gb = Wp + (size_t)(n0 + (t >> 2)) * Kp + (t & 3) * 8;
    char* lA = (char*)As + w * 1024;
    char* lB = (char*)Bs + w * 1024;
    for (int k0 = 0; k0 < Kp; k0 += 32) {
        __syncthreads();
        __builtin_amdgcn_global_load_lds(
            (const __attribute__((address_space(1))) unsigned int*)(ga + k0),
            (__attribute__((address_space(3))) unsigned int*)lA, 16, 0, 0);
        __builtin_amdgcn_global_load_lds(
            (const __attribute__((address_space(1))) unsigned int*)(ga + (size_t)64 * Kp + k0),
            (__attribute__((address_space(3))) unsigned int*)(lA + 4096), 16, 0, 0);
        __builtin_amdgcn_global_load_lds(
            (const __attribute__((address_space(1))) unsigned int*)(gb + k0),
            (__attribute__((address_space(3))) unsigned int*)lB, 16, 0, 0);
        __builtin_amdgcn_global_load_lds(
            (const __attribute__((address_space(1))) unsigned int*)(gb + (size_t)64 * Kp + k0),
            (__attribute__((address_space(3))) unsigned int*)(lB + 4096), 16, 0, 0);
        __syncthreads();
        bf16x8 af[4], bfr[4];
        #pragma unroll
        for (int m = 0; m < 4; ++m)
            af[m] = *(const bf16x8*)&As[(wr + m * 16 + lrow) * 32 + lk8];
        #pragma unroll
        for (int n = 0; n < 4; ++n)
            bfr[n] = *(const bf16x8*)&Bs[(wc + n * 16 + lrow) * 32 + lk8];
        #pragma unroll
        for (int m = 0; m < 4; ++m)
            #pragma unroll
            for (int n = 0; n < 4; ++n)
                acc[m][n] = __builtin_amdgcn_mfma_f32_16x16x32_bf16(
                    af[m], bfr[n], acc[m][n], 0, 0, 0);
    }
    #pragma unroll
    for (int m = 0; m < 4; ++m) {
        #pragma unroll
        for (int n = 0; n < 4; ++n) {
            #pragma unroll
            for (int j = 0; j < 4; ++j) {
                int row = m0 + wr + m * 16 + (l >> 4) * 4 + j;
                int col = n0 + wc + n * 16 + (l & 15);
                float v = acc[m][n][j];
                if (EPI == 0) {
                    if (col < splitN) C0[(size_t)row * ldout + col] = v;
                    else              C1[(size_t)row * ldout + (col - splitN)] = v;
                } else {
                    C0[(size_t)row * ldout + col] = v + resid[(size_t)row * ldout + col];
                }
            }
        }
    }
}

/* ---- fp32 GEMM for the small projections ---- */
#define BM 64
#define BN 64
#define BK 16
template<int EPI>
__global__ __launch_bounds__(256) void gemm_kernel(
        const float* __restrict__ A, int lda,
        const float* __restrict__ W,
        float* __restrict__ C0, int ldc0,
        const float* __restrict__ bias,
        int M, int N, int K) {
    __shared__ float As[BK][BM + 4];
    __shared__ float Bs[BK][BN + 4];
    const int m0 = blockIdx.y * BM;
    const int n0 = blockIdx.x * BN;
    const int t  = threadIdx.x;
    const int lr = t >> 2;
    const int lk = (t & 3) << 2;
    const int tm = (t & 15) << 2;
    const int tn = (t >> 4) << 2;
    float acc[4][4] = {};
    for (int k0 = 0; k0 < K; k0 += BK) {
        float4 av = *(const float4*)(A + (size_t)(m0 + lr) * lda + k0 + lk);
        float4 bv = make_float4(0.f, 0.f, 0.f, 0.f);
        int wrow = n0 + lr;
        if (wrow < N) bv = *(const float4*)(W + (size_t)wrow * K + k0 + lk);
        __syncthreads();
        As[lk + 0][lr] = av.x; As[lk + 1][lr] = av.y;
        As[lk + 2][lr] = av.z; As[lk + 3][lr] = av.w;
        Bs[lk + 0][lr] = bv.x; Bs[lk + 1][lr] = bv.y;
        Bs[lk + 2][lr] = bv.z; Bs[lk + 3][lr] = bv.w;
        __syncthreads();
        #pragma unroll
        for (int k = 0; k < BK; ++k) {
            float4 a = *(const float4*)&As[k][tm];
            float4 b = *(const float4*)&Bs[k][tn];
            acc[0][0] += a.x*b.x; acc[0][1] += a.x*b.y; acc[0][2] += a.x*b.z; acc[0][3] += a.x*b.w;
            acc[1][0] += a.y*b.x; acc[1][1] += a.y*b.y; acc[1][2] += a.y*b.z; acc[1][3] += a.y*b.w;
            acc[2][0] += a.z*b.x; acc[2][1] += a.z*b.y; acc[2][2] += a.z*b.z; acc[2][3] += a.z*b.w;
            acc[3][0] += a.w*b.x; acc[3][1] += a.w*b.y; acc[3][2] += a.w*b.z; acc[3][3] += a.w*b.w;
        }
    }
    #pragma unroll
    for (int i = 0; i < 4; ++i) {
        int row = m0 + tm + i;
        #pragma unroll
        for (int j = 0; j < 4; ++j) {
            int col = n0 + tn + j;
            if (col >= N) continue;
            float v = acc[i][j];
            if (EPI == 0) C0[(size_t)row * ldc0 + col] = v;
            else          C0[(size_t)row * ldc0 + col] = softplus_f(v + bias[col]);
        }
    }
}

/* ---- causal depthwise conv (d_conv=4) + SiLU ---- */
__global__ __launch_bounds__(256) void conv_silu_kernel(
        const float* __restrict__ xi, const float* __restrict__ w,
        const float* __restrict__ b, float* __restrict__ xc) {
    size_t i = (size_t)blockIdx.x * 256 + threadIdx.x;
    int d = (int)(i & (D_INNER - 1));
    int tt = (int)(i >> 11);
    int s = tt & (SEQ - 1);
    float4 wv = ((const float4*)w)[d];
    float acc = b[d];
    if (s >= 3) acc += wv.x * xi[i - 3 * D_INNER];
    if (s >= 2) acc += wv.y * xi[i - 2 * D_INNER];
    if (s >= 1) acc += wv.z * xi[i - 1 * D_INNER];
    acc += wv.w * xi[i];
    xc[i] = silu_f(acc);
}

/* =====================================================================
   Selective scan, thread-per-(b,d,chunk), 16 states in registers.
   B[t,n] / C[t,n] are wave-uniform -> scalar (s_load) path, zero LDS.
   ===================================================================== */

/* pass A: per-chunk summaries (hpart = zero-state h, P = prod dA) */
__global__ __launch_bounds__(256) void scanA_kernel(
        const float* __restrict__ xc, const float* __restrict__ delta,
        const float* __restrict__ xdbl, const float* __restrict__ A_log,
        float* __restrict__ hpart, float* __restrict__ Pp) {
    const int bid = blockIdx.x;            /* 512 blocks */
    const int b    = bid >> 8;
    const int c    = (bid >> 3) & 31;
    const int dblk = bid & 7;
    const int d    = (dblk << 8) + threadIdx.x;
    float adn[NSTATE];
    #pragma unroll
    for (int k = 0; k < 4; ++k) {
        float4 a = *(const float4*)(A_log + d * NSTATE + k * 4);
        adn[k*4+0] = -__expf(a.x); adn[k*4+1] = -__expf(a.y);
        adn[k*4+2] = -__expf(a.z); adn[k*4+3] = -__expf(a.w);
    }
    float h[NSTATE], P[NSTATE];
    #pragma unroll
    for (int n = 0; n < NSTATE; ++n) { h[n] = 0.f; P[n] = 1.f; }
    const int rowbase = b * SEQ + c * CHL;
    #pragma unroll 4
    for (int r = 0; r < CHL; ++r) {
        const int row = rowbase + r;
        const float* brow = xdbl + (size_t)row * XDBL + DT_RANK;  /* uniform addr */
        float dl = delta[(size_t)row * D_INNER + d];
        float u  = xc[(size_t)row * D_INNER + d];
        float du = dl * u;
        #pragma unroll
        for (int n = 0; n < NSTATE; ++n) {
            float dA = __expf(dl * adn[n]);
            h[n] = fmaf(dA, h[n], du * brow[n]);
            P[n] *= dA;
        }
    }
    size_t base = (size_t)c * BDN + (size_t)(b * D_INNER + d) * NSTATE;
    #pragma unroll
    for (int k = 0; k < 4; ++k) {
        *(float4*)(hpart + base + k * 4) = make_float4(h[k*4], h[k*4+1], h[k*4+2], h[k*4+3]);
        *(float4*)(Pp    + base + k * 4) = make_float4(P[k*4], P[k*4+1], P[k*4+2], P[k*4+3]);
    }
}

/* pass B: scan the 32 chunk summaries -> h_start per chunk */
__global__ __launch_bounds__(256) void scanB_kernel(
        const float* __restrict__ hpart, const float* __restrict__ Pp,
        float* __restrict__ hstart) {
    int idx = blockIdx.x * 256 + threadIdx.x;
    float h = 0.f;
    for (int c = 0; c < NCH; ++c) {
        hstart[(size_t)c * BDN + idx] = h;
        h = fmaf(Pp[(size_t)c * BDN + idx], h, hpart[(size_t)c * BDN + idx]);
    }
}

/* pass C: replay with true h_start; fused y, gate, split-bf16 pack */
__global__ __launch_bounds__(256) void scanC_kernel(
        const float* __restrict__ xc, const float* __restrict__ delta,
        const float* __restrict__ xdbl, const float* __restrict__ A_log,
        const float* __restrict__ Dp, const float* __restrict__ hstart,
        const float* __restrict__ res, unsigned short* __restrict__ y_p) {
    const int bid = blockIdx.x;
    const int b    = bid >> 8;
    const int c    = (bid >> 3) & 31;
    const int dblk = bid & 7;
    const int d    = (dblk << 8) + threadIdx.x;
    float adn[NSTATE];
    #pragma unroll
    for (int k = 0; k < 4; ++k) {
        float4 a = *(const float4*)(A_log + d * NSTATE + k * 4);
        adn[k*4+0] = -__expf(a.x); adn[k*4+1] = -__expf(a.y);
        adn[k*4+2] = -__expf(a.z); adn[k*4+3] = -__expf(a.w);
    }
    const float Dd = Dp[d];
    float h[NSTATE];
    size_t base = (size_t)c * BDN + (size_t)(b * D_INNER + d) * NSTATE;
    #pragma unroll
    for (int k = 0; k < 4; ++k) {
        float4 hv = *(const float4*)(hstart + base + k * 4);
        h[k*4] = hv.x; h[k*4+1] = hv.y; h[k*4+2] = hv.z; h[k*4+3] = hv.w;
    }
    const int rowbase = b * SEQ + c * CHL;
    #pragma unroll 4
    for (int r = 0; r < CHL; ++r) {
        const int row = rowbase + r;
        const float* brow = xdbl + (size_t)row * XDBL + DT_RANK;       /* uniform */
        const float* crow = brow + NSTATE;                              /* uniform */
        float dl = delta[(size_t)row * D_INNER + d];
        float u  = xc[(size_t)row * D_INNER + d];
        float du = dl * u;
        float ysum = u * Dd;
        #pragma unroll
        for (int n = 0; n < NSTATE; ++n) {
            float dA = __expf(dl * adn[n]);
            h[n] = fmaf(dA, h[n], du * brow[n]);
            ysum = fmaf(h[n], crow[n], ysum);
        }
        float rv = res[(size_t)row * D_INNER + d];
        float gv = ysum * silu_f(rv);
        unsigned short hi = f2bf(gv);
        unsigned short lo = f2bf(gv - bf2f(hi));
        size_t o = (size_t)row * (3 * D_INNER) + d;
        y_p[o]               = hi;
        y_p[o + D_INNER]     = hi;
        y_p[o + 2 * D_INNER] = lo;
    }
}

extern "C" void kernel_launch(void* const* d_in, const int* in_sizes, int n_in,
                              void* d_out, int out_size, void* d_ws, size_t ws_size,
                              hipStream_t stream) {
    const float* x         = (const float*)d_in[0];
    const float* norm_w    = (const float*)d_in[1];
    const float* in_proj_w = (const float*)d_in[2];
    const float* conv_w    = (const float*)d_in[3];
    const float* conv_b    = (const float*)d_in[4];
    const float* x_proj_w  = (const float*)d_in[5];
    const float* dt_proj_w = (const float*)d_in[6];
    const float* dt_proj_b = (const float*)d_in[7];
    const float* A_log     = (const float*)d_in[8];
    const float* Dp        = (const float*)d_in[9];
    const float* out_proj_w= (const float*)d_in[10];
    float* out = (float*)d_out;
    float* ws  = (float*)d_ws;

    const size_t M8 = (size_t)T_TOK * D_INNER;
    float* res   = ws;
    float* xc    = res + M8;
    float* delta = xc + M8;
    float* xdbl  = delta + M8;
    unsigned short* xn_p   = (unsigned short*)(xdbl + (size_t)T_TOK * XDBL);
    unsigned short* w_in_p = xn_p + (size_t)4096 * 3072;
    unsigned short* w_out_p= w_in_p + (size_t)4096 * 3072;
    unsigned short* y_p    = xn_p;             /* alias: dead after in_proj */
    float* xi    = (float*)(w_out_p + (size_t)1024 * 6144);
    float* hpart = xi;                         /* alias: dead after conv */
    float* Pp    = xi + (size_t)BDN * NCH;
    float* hstart= Pp + (size_t)BDN * NCH;

    wpack_kernel<<<4096, 256, 0, stream>>>(in_proj_w,  w_in_p,  HIDDEN);
    wpack_kernel<<<2048, 256, 0, stream>>>(out_proj_w, w_out_p, D_INNER);

    rmsnorm_pack_kernel<<<T_TOK, 256, 0, stream>>>(x, norm_w, xn_p);

    { /* in_proj (MFMA split-bf16) */
        dim3 g(4096 / 128, T_TOK / 128);
        mgemm_kernel<0><<<g, 256, 0, stream>>>(xn_p, w_in_p, 3 * HIDDEN,
                                               xi, res, D_INNER, nullptr, D_INNER);
    }

    conv_silu_kernel<<<(int)(M8 / 256), 256, 0, stream>>>(xi, conv_w, conv_b, xc);

    { /* x_proj (fp32) */
        dim3 g((XDBL + BN - 1) / BN, T_TOK / BM);
        gemm_kernel<0><<<g, 256, 0, stream>>>(xc, D_INNER, x_proj_w, xdbl, XDBL,
                                              nullptr, T_TOK, XDBL, D_INNER);
    }
    { /* dt_proj + softplus (fp32) */
        dim3 g(D_INNER / BN, T_TOK / BM);
        gemm_kernel<2><<<g, 256, 0, stream>>>(xdbl, XDBL, dt_proj_w, delta, D_INNER,
                                              dt_proj_b, T_TOK, D_INNER, DT_RANK);
    }

    scanA_kernel<<<512, 256, 0, stream>>>(xc, delta, xdbl, A_log, hpart, Pp);
    scanB_kernel<<<BDN / 256, 256, 0, stream>>>(hpart, Pp, hstart);
    scanC_kernel<<<512, 256, 0, stream>>>(xc, delta, xdbl, A_log, Dp, hstart, res, y_p);

    { /* out_proj (MFMA split-bf16) + residual */
        dim3 g(HIDDEN / 128, T_TOK / 128);
        mgemm_kernel<1><<<g, 256, 0, stream>>>(y_p, w_out_p, 3 * D_INNER,
                                               out, nullptr, 0, x, HIDDEN);
    }
}

// Round 4
// 498.163 us; speedup vs baseline: 2.6037x; 1.1276x over previous
//
#include <hip/hip_runtime.h>
#include <math.h>

#define HIDDEN   1024
#define D_INNER  2048
#define NSTATE   16
#define DT_RANK  64
#define BATCH    2
#define SEQ      2048
#define T_TOK    (BATCH * SEQ)            /* 4096 tokens */
#define XDBL     (DT_RANK + 2 * NSTATE)   /* 96 */
#define NCH      32                       /* scan chunks */
#define CHL      (SEQ / NCH)              /* 64 steps per chunk */
#define BDN      (BATCH * D_INNER * NSTATE) /* 65536 */

typedef float f32x4   __attribute__((ext_vector_type(4)));
typedef short bf16x8  __attribute__((ext_vector_type(8)));
typedef short short4v __attribute__((ext_vector_type(4)));

#define AS1 __attribute__((address_space(1)))
#define AS3 __attribute__((address_space(3)))

__device__ __forceinline__ float silu_f(float x) { return x / (1.0f + __expf(-x)); }
__device__ __forceinline__ float softplus_f(float x) {
    return fmaxf(x, 0.0f) + log1pf(__expf(-fabsf(x)));
}
__device__ __forceinline__ unsigned short f2bf(float x) {
    unsigned int u = __float_as_uint(x);
    u += 0x7fffu + ((u >> 16) & 1u);           /* RNE */
    return (unsigned short)(u >> 16);
}
__device__ __forceinline__ float bf2f(unsigned short h) {
    return __uint_as_float(((unsigned int)h) << 16);
}

/* ---- weight split-pack: W[rows,K] fp32 -> Wp[rows,3K] bf16 = [hi|lo|hi] ---- */
__global__ __launch_bounds__(256) void wpack_kernel(
        const float* __restrict__ w, unsigned short* __restrict__ wp, int K) {
    int i = blockIdx.x * 256 + threadIdx.x;
    int kq = K >> 2;
    int row = i / kq;
    int c = (i - row * kq) << 2;
    float4 v = *(const float4*)(w + (size_t)row * K + c);
    short4v hi, lo;
    hi.x = f2bf(v.x); hi.y = f2bf(v.y); hi.z = f2bf(v.z); hi.w = f2bf(v.w);
    lo.x = f2bf(v.x - bf2f(hi.x)); lo.y = f2bf(v.y - bf2f(hi.y));
    lo.z = f2bf(v.z - bf2f(hi.z)); lo.w = f2bf(v.w - bf2f(hi.w));
    size_t b0 = (size_t)row * (3 * K) + c;
    *(short4v*)(wp + b0)         = hi;
    *(short4v*)(wp + b0 + K)     = lo;
    *(short4v*)(wp + b0 + 2 * K) = hi;
}

/* ---- RMSNorm fused with split-pack: x[row,1024] -> xn_p[row,3072]=[hi|hi|lo] ---- */
__global__ __launch_bounds__(256) void rmsnorm_pack_kernel(
        const float* __restrict__ x, const float* __restrict__ w,
        unsigned short* __restrict__ xn_p) {
    int row = blockIdx.x;
    float4 v = ((const float4*)(x + (size_t)row * HIDDEN))[threadIdx.x];
    float ss = v.x*v.x + v.y*v.y + v.z*v.z + v.w*v.w;
    #pragma unroll
    for (int off = 32; off; off >>= 1) ss += __shfl_down(ss, off);
    __shared__ float wsum[4];
    if ((threadIdx.x & 63) == 0) wsum[threadIdx.x >> 6] = ss;
    __syncthreads();
    float scale = rsqrtf((wsum[0] + wsum[1] + wsum[2] + wsum[3]) / (float)HIDDEN + 1e-5f);
    float4 wv = ((const float4*)w)[threadIdx.x];
    float o0 = v.x * scale * wv.x, o1 = v.y * scale * wv.y;
    float o2 = v.z * scale * wv.z, o3 = v.w * scale * wv.w;
    short4v hi, lo;
    hi.x = f2bf(o0); hi.y = f2bf(o1); hi.z = f2bf(o2); hi.w = f2bf(o3);
    lo.x = f2bf(o0 - bf2f(hi.x)); lo.y = f2bf(o1 - bf2f(hi.y));
    lo.z = f2bf(o2 - bf2f(hi.z)); lo.w = f2bf(o3 - bf2f(hi.w));
    size_t b0 = (size_t)row * (3 * HIDDEN) + threadIdx.x * 4;
    *(short4v*)&xn_p[b0]              = hi;
    *(short4v*)&xn_p[b0 + HIDDEN]     = hi;
    *(short4v*)&xn_p[b0 + 2 * HIDDEN] = lo;
}

/* ---- bf16 MFMA GEMM: 128x128 tile, BK=64, both-sides XOR-swizzled LDS ----
   C[M,N] = Ap[M,Kp] @ Wp[N,Kp]^T   (k-range [z*klen, (z+1)*klen))
   EPI 0: col<splitN -> C0 else C1 (in_proj)
   EPI 2: partial store to C0 + z*partStride (out_proj split-K)          */
template<int EPI>
__global__ __launch_bounds__(256) void mgemm_kernel(
        const unsigned short* __restrict__ Ap, const unsigned short* __restrict__ Wp,
        int Kp, int klen, float* __restrict__ C0, float* __restrict__ C1,
        int splitN, int ldout, size_t partStride) {
    __shared__ short As[128 * 64];
    __shared__ short Bs[128 * 64];
    const int t = threadIdx.x;
    const int w = t >> 6, l = t & 63;
    const int m0 = blockIdx.y * 128, n0 = blockIdx.x * 128;
    const int kbeg = blockIdx.z * klen;
    const int wr = (w >> 1) * 64, wc = (w & 1) * 64;
    const int lrow = l & 15;
    f32x4 acc[4][4];
    #pragma unroll
    for (int m = 0; m < 4; ++m)
        #pragma unroll
        for (int n = 0; n < 4; ++n) {
            acc[m][n].x = 0.f; acc[m][n].y = 0.f; acc[m][n].z = 0.f; acc[m][n].w = 0.f;
        }
    /* staging: wave w fills rows [w*32, w*32+32). Per instr q: 8 rows.
       lane l -> row_off = l>>3, LDS col8-slot = l&7.
       Pre-swizzled global source col8 = (l&7) ^ ((l>>3)&7) so that
       LDS[row][c8] = global[row][c8 ^ (row&7)]  (row&7 == (l>>3)&7).   */
    const int srow = w * 32 + (l >> 3);
    const int sc8  = (l & 7) ^ ((l >> 3) & 7);
    const unsigned short* gaw = Ap + (size_t)(m0 + srow) * Kp + sc8 * 8;
    const unsigned short* gbw = Wp + (size_t)(n0 + srow) * Kp + sc8 * 8;
    for (int k0 = kbeg; k0 < kbeg + klen; k0 += 64) {
        __syncthreads();
        #pragma unroll
        for (int q = 0; q < 4; ++q) {
            __builtin_amdgcn_global_load_lds(
                (const AS1 unsigned int*)(gaw + k0 + (size_t)q * 8 * Kp),
                (AS3 unsigned int*)((char*)As + (w * 32 + q * 8) * 128), 16, 0, 0);
            __builtin_amdgcn_global_load_lds(
                (const AS1 unsigned int*)(gbw + k0 + (size_t)q * 8 * Kp),
                (AS3 unsigned int*)((char*)Bs + (w * 32 + q * 8) * 128), 16, 0, 0);
        }
        __syncthreads();
        /* read side: row = (sub-tile row), want global slot s = kk*4 + (l>>4);
           read LDS slot s ^ (row&7), row&7 == l&7. */
        #pragma unroll
        for (int kk = 0; kk < 2; ++kk) {
            const int slot = ((kk * 4 + (l >> 4)) ^ (l & 7)) * 8;
            bf16x8 af[4], bfr[4];
            #pragma unroll
            for (int m = 0; m < 4; ++m)
                af[m] = *(const bf16x8*)&As[(wr + m * 16 + lrow) * 64 + slot];
            #pragma unroll
            for (int n = 0; n < 4; ++n)
                bfr[n] = *(const bf16x8*)&Bs[(wc + n * 16 + lrow) * 64 + slot];
            #pragma unroll
            for (int m = 0; m < 4; ++m)
                #pragma unroll
                for (int n = 0; n < 4; ++n)
                    acc[m][n] = __builtin_amdgcn_mfma_f32_16x16x32_bf16(
                        af[m], bfr[n], acc[m][n], 0, 0, 0);
        }
    }
    float* dst = (EPI == 2) ? (C0 + blockIdx.z * partStride) : C0;
    #pragma unroll
    for (int m = 0; m < 4; ++m) {
        #pragma unroll
        for (int n = 0; n < 4; ++n) {
            #pragma unroll
            for (int j = 0; j < 4; ++j) {
                int row = m0 + wr + m * 16 + (l >> 4) * 4 + j;
                int col = n0 + wc + n * 16 + (l & 15);
                float v = acc[m][n][j];
                if (EPI == 0) {
                    if (col < splitN) C0[(size_t)row * ldout + col] = v;
                    else              C1[(size_t)row * ldout + (col - splitN)] = v;
                } else {
                    dst[(size_t)row * ldout + col] = v;
                }
            }
        }
    }
}

/* ---- reduce 4 split-K partials + residual x -> out ---- */
__global__ __launch_bounds__(256) void reduce4_kernel(
        const float* __restrict__ parts, size_t partStride,
        const float* __restrict__ x, float* __restrict__ out) {
    size_t i = (size_t)blockIdx.x * 256 + threadIdx.x;   /* float4 index */
    float4 a = ((const float4*)(parts))[i];
    float4 b = ((const float4*)(parts + partStride))[i];
    float4 c = ((const float4*)(parts + 2 * partStride))[i];
    float4 d = ((const float4*)(parts + 3 * partStride))[i];
    float4 xv = ((const float4*)x)[i];
    float4 o;
    o.x = a.x + b.x + c.x + d.x + xv.x;
    o.y = a.y + b.y + c.y + d.y + xv.y;
    o.z = a.z + b.z + c.z + d.z + xv.z;
    o.w = a.w + b.w + c.w + d.w + xv.w;
    ((float4*)out)[i] = o;
}

/* ---- fp32 GEMM for the small projections ---- */
#define BM 64
#define BN 64
#define BK 16
template<int EPI>
__global__ __launch_bounds__(256) void gemm_kernel(
        const float* __restrict__ A, int lda,
        const float* __restrict__ W,
        float* __restrict__ C0, int ldc0,
        const float* __restrict__ bias,
        int M, int N, int K) {
    __shared__ float As[BK][BM + 4];
    __shared__ float Bs[BK][BN + 4];
    const int m0 = blockIdx.y * BM;
    const int n0 = blockIdx.x * BN;
    const int t  = threadIdx.x;
    const int lr = t >> 2;
    const int lk = (t & 3) << 2;
    const int tm = (t & 15) << 2;
    const int tn = (t >> 4) << 2;
    float acc[4][4] = {};
    for (int k0 = 0; k0 < K; k0 += BK) {
        float4 av = *(const float4*)(A + (size_t)(m0 + lr) * lda + k0 + lk);
        float4 bv = make_float4(0.f, 0.f, 0.f, 0.f);
        int wrow = n0 + lr;
        if (wrow < N) bv = *(const float4*)(W + (size_t)wrow * K + k0 + lk);
        __syncthreads();
        As[lk + 0][lr] = av.x; As[lk + 1][lr] = av.y;
        As[lk + 2][lr] = av.z; As[lk + 3][lr] = av.w;
        Bs[lk + 0][lr] = bv.x; Bs[lk + 1][lr] = bv.y;
        Bs[lk + 2][lr] = bv.z; Bs[lk + 3][lr] = bv.w;
        __syncthreads();
        #pragma unroll
        for (int k = 0; k < BK; ++k) {
            float4 a = *(const float4*)&As[k][tm];
            float4 b = *(const float4*)&Bs[k][tn];
            acc[0][0] += a.x*b.x; acc[0][1] += a.x*b.y; acc[0][2] += a.x*b.z; acc[0][3] += a.x*b.w;
            acc[1][0] += a.y*b.x; acc[1][1] += a.y*b.y; acc[1][2] += a.y*b.z; acc[1][3] += a.y*b.w;
            acc[2][0] += a.z*b.x; acc[2][1] += a.z*b.y; acc[2][2] += a.z*b.z; acc[2][3] += a.z*b.w;
            acc[3][0] += a.w*b.x; acc[3][1] += a.w*b.y; acc[3][2] += a.w*b.z; acc[3][3] += a.w*b.w;
        }
    }
    #pragma unroll
    for (int i = 0; i < 4; ++i) {
        int row = m0 + tm + i;
        #pragma unroll
        for (int j = 0; j < 4; ++j) {
            int col = n0 + tn + j;
            if (col >= N) continue;
            float v = acc[i][j];
            if (EPI == 0) C0[(size_t)row * ldc0 + col] = v;
            else          C0[(size_t)row * ldc0 + col] = softplus_f(v + bias[col]);
        }
    }
}

/* ---- causal depthwise conv (d_conv=4) + SiLU ---- */
__global__ __launch_bounds__(256) void conv_silu_kernel(
        const float* __restrict__ xi, const float* __restrict__ w,
        const float* __restrict__ b, float* __restrict__ xc) {
    size_t i = (size_t)blockIdx.x * 256 + threadIdx.x;
    int d = (int)(i & (D_INNER - 1));
    int tt = (int)(i >> 11);
    int s = tt & (SEQ - 1);
    float4 wv = ((const float4*)w)[d];
    float acc = b[d];
    if (s >= 3) acc += wv.x * xi[i - 3 * D_INNER];
    if (s >= 2) acc += wv.y * xi[i - 2 * D_INNER];
    if (s >= 1) acc += wv.z * xi[i - 1 * D_INNER];
    acc += wv.w * xi[i];
    xc[i] = silu_f(acc);
}

/* ==== selective scan: thread-per-(b,d,chunk), states in registers ==== */

__global__ __launch_bounds__(256) void scanA_kernel(
        const float* __restrict__ xc, const float* __restrict__ delta,
        const float* __restrict__ xdbl, const float* __restrict__ A_log,
        float* __restrict__ hpart, float* __restrict__ Pp) {
    const int bid = blockIdx.x;            /* 512 blocks */
    const int b    = bid >> 8;
    const int c    = (bid >> 3) & 31;
    const int dblk = bid & 7;
    const int d    = (dblk << 8) + threadIdx.x;
    float adn[NSTATE];
    #pragma unroll
    for (int k = 0; k < 4; ++k) {
        float4 a = *(const float4*)(A_log + d * NSTATE + k * 4);
        adn[k*4+0] = -__expf(a.x); adn[k*4+1] = -__expf(a.y);
        adn[k*4+2] = -__expf(a.z); adn[k*4+3] = -__expf(a.w);
    }
    float h[NSTATE], P[NSTATE];
    #pragma unroll
    for (int n = 0; n < NSTATE; ++n) { h[n] = 0.f; P[n] = 1.f; }
    const int rowbase = b * SEQ + c * CHL;
    #pragma unroll 4
    for (int r = 0; r < CHL; ++r) {
        const int row = rowbase + r;
        const float* brow = xdbl + (size_t)row * XDBL + DT_RANK;  /* uniform addr */
        float dl = delta[(size_t)row * D_INNER + d];
        float u  = xc[(size_t)row * D_INNER + d];
        float du = dl * u;
        #pragma unroll
        for (int n = 0; n < NSTATE; ++n) {
            float dA = __expf(dl * adn[n]);
            h[n] = fmaf(dA, h[n], du * brow[n]);
            P[n] *= dA;
        }
    }
    size_t base = (size_t)c * BDN + (size_t)(b * D_INNER + d) * NSTATE;
    #pragma unroll
    for (int k = 0; k < 4; ++k) {
        *(float4*)(hpart + base + k * 4) = make_float4(h[k*4], h[k*4+1], h[k*4+2], h[k*4+3]);
        *(float4*)(Pp    + base + k * 4) = make_float4(P[k*4], P[k*4+1], P[k*4+2], P[k*4+3]);
    }
}

__global__ __launch_bounds__(256) void scanB_kernel(
        const float* __restrict__ hpart, const float* __restrict__ Pp,
        float* __restrict__ hstart) {
    int idx = blockIdx.x * 256 + threadIdx.x;
    float h = 0.f;
    for (int c = 0; c < NCH; ++c) {
        hstart[(size_t)c * BDN + idx] = h;
        h = fmaf(Pp[(size_t)c * BDN + idx], h, hpart[(size_t)c * BDN + idx]);
    }
}

__global__ __launch_bounds__(256) void scanC_kernel(
        const float* __restrict__ xc, const float* __restrict__ delta,
        const float* __restrict__ xdbl, const float* __restrict__ A_log,
        const float* __restrict__ Dp, const float* __restrict__ hstart,
        const float* __restrict__ res, unsigned short* __restrict__ y_p) {
    const int bid = blockIdx.x;
    const int b    = bid >> 8;
    const int c    = (bid >> 3) & 31;
    const int dblk = bid & 7;
    const int d    = (dblk << 8) + threadIdx.x;
    float adn[NSTATE];
    #pragma unroll
    for (int k = 0; k < 4; ++k) {
        float4 a = *(const float4*)(A_log + d * NSTATE + k * 4);
        adn[k*4+0] = -__expf(a.x); adn[k*4+1] = -__expf(a.y);
        adn[k*4+2] = -__expf(a.z); adn[k*4+3] = -__expf(a.w);
    }
    const float Dd = Dp[d];
    float h[NSTATE];
    size_t base = (size_t)c * BDN + (size_t)(b * D_INNER + d) * NSTATE;
    #pragma unroll
    for (int k = 0; k < 4; ++k) {
        float4 hv = *(const float4*)(hstart + base + k * 4);
        h[k*4] = hv.x; h[k*4+1] = hv.y; h[k*4+2] = hv.z; h[k*4+3] = hv.w;
    }
    const int rowbase = b * SEQ + c * CHL;
    #pragma unroll 4
    for (int r = 0; r < CHL; ++r) {
        const int row = rowbase + r;
        const float* brow = xdbl + (size_t)row * XDBL + DT_RANK;       /* uniform */
        const float* crow = brow + NSTATE;                              /* uniform */
        float dl = delta[(size_t)row * D_INNER + d];
        float u  = xc[(size_t)row * D_INNER + d];
        float du = dl * u;
        float ysum = u * Dd;
        #pragma unroll
        for (int n = 0; n < NSTATE; ++n) {
            float dA = __expf(dl * adn[n]);
            h[n] = fmaf(dA, h[n], du * brow[n]);
            ysum = fmaf(h[n], crow[n], ysum);
        }
        float rv = res[(size_t)row * D_INNER + d];
        float gv = ysum * silu_f(rv);
        unsigned short hi = f2bf(gv);
        unsigned short lo = f2bf(gv - bf2f(hi));
        size_t o = (size_t)row * (3 * D_INNER) + d;
        y_p[o]               = hi;
        y_p[o + D_INNER]     = hi;
        y_p[o + 2 * D_INNER] = lo;
    }
}

extern "C" void kernel_launch(void* const* d_in, const int* in_sizes, int n_in,
                              void* d_out, int out_size, void* d_ws, size_t ws_size,
                              hipStream_t stream) {
    const float* x         = (const float*)d_in[0];
    const float* norm_w    = (const float*)d_in[1];
    const float* in_proj_w = (const float*)d_in[2];
    const float* conv_w    = (const float*)d_in[3];
    const float* conv_b    = (const float*)d_in[4];
    const float* x_proj_w  = (const float*)d_in[5];
    const float* dt_proj_w = (const float*)d_in[6];
    const float* dt_proj_b = (const float*)d_in[7];
    const float* A_log     = (const float*)d_in[8];
    const float* Dp        = (const float*)d_in[9];
    const float* out_proj_w= (const float*)d_in[10];
    float* out = (float*)d_out;
    float* ws  = (float*)d_ws;

    const size_t M8 = (size_t)T_TOK * D_INNER;
    float* res   = ws;                                   /* dead after scanC */
    float* xc    = res + M8;                             /* dead after scanC */
    float* delta = xc + M8;                              /* dead after scanC */
    float* xdbl  = delta + M8;
    unsigned short* xn_p   = (unsigned short*)(xdbl + (size_t)T_TOK * XDBL);
    unsigned short* w_in_p = xn_p + (size_t)4096 * 3072;
    unsigned short* w_out_p= w_in_p + (size_t)4096 * 3072;
    unsigned short* y_p    = xn_p;             /* alias: dead after in_proj */
    float* xi    = (float*)(w_out_p + (size_t)1024 * 6144);
    float* hpart = xi;                         /* alias: dead after conv */
    float* Pp    = xi + (size_t)BDN * NCH;
    float* hstart= Pp + (size_t)BDN * NCH;
    float* parts = ws;                         /* alias res+xc: 16M floats for 4 partials */
    const size_t partStride = (size_t)T_TOK * HIDDEN;    /* 4194304 */

    wpack_kernel<<<4096, 256, 0, stream>>>(in_proj_w,  w_in_p,  HIDDEN);
    wpack_kernel<<<2048, 256, 0, stream>>>(out_proj_w, w_out_p, D_INNER);

    rmsnorm_pack_kernel<<<T_TOK, 256, 0, stream>>>(x, norm_w, xn_p);

    { /* in_proj (MFMA split-bf16): grid (32,32,1) */
        dim3 g(4096 / 128, T_TOK / 128, 1);
        mgemm_kernel<0><<<g, 256, 0, stream>>>(xn_p, w_in_p, 3 * HIDDEN, 3 * HIDDEN,
                                               xi, res, D_INNER, D_INNER, 0);
    }

    conv_silu_kernel<<<(int)(M8 / 256), 256, 0, stream>>>(xi, conv_w, conv_b, xc);

    { /* x_proj (fp32) */
        dim3 g((XDBL + BN - 1) / BN, T_TOK / BM);
        gemm_kernel<0><<<g, 256, 0, stream>>>(xc, D_INNER, x_proj_w, xdbl, XDBL,
                                              nullptr, T_TOK, XDBL, D_INNER);
    }
    { /* dt_proj + softplus (fp32) */
        dim3 g(D_INNER / BN, T_TOK / BM);
        gemm_kernel<2><<<g, 256, 0, stream>>>(xdbl, XDBL, dt_proj_w, delta, D_INNER,
                                              dt_proj_b, T_TOK, D_INNER, DT_RANK);
    }

    scanA_kernel<<<512, 256, 0, stream>>>(xc, delta, xdbl, A_log, hpart, Pp);
    scanB_kernel<<<BDN / 256, 256, 0, stream>>>(hpart, Pp, hstart);
    scanC_kernel<<<512, 256, 0, stream>>>(xc, delta, xdbl, A_log, Dp, hstart, res, y_p);

    { /* out_proj (MFMA split-bf16, split-K=4): grid (8,32,4) */
        dim3 g(HIDDEN / 128, T_TOK / 128, 4);
        mgemm_kernel<2><<<g, 256, 0, stream>>>(y_p, w_out_p, 3 * D_INNER, 6144 / 4,
                                               parts, nullptr, 0, HIDDEN, partStride);
    }
    /* residual + reduce */
    reduce4_kernel<<<(int)(partStride / 4 / 256), 256, 0, stream>>>(parts, partStride, x, out);
}

// Round 5
// 397.303 us; speedup vs baseline: 3.2646x; 1.2539x over previous
//
#include <hip/hip_runtime.h>
#include <math.h>

#define HIDDEN   1024
#define D_INNER  2048
#define NSTATE   16
#define DT_RANK  64
#define BATCH    2
#define SEQ      2048
#define T_TOK    (BATCH * SEQ)            /* 4096 tokens */
#define XDBL     (DT_RANK + 2 * NSTATE)   /* 96 */
#define NCH      32                       /* scan chunks */
#define CHL      (SEQ / NCH)              /* 64 steps per chunk */
#define BDN      (BATCH * D_INNER * NSTATE) /* 65536 */

typedef float f32x4   __attribute__((ext_vector_type(4)));
typedef short bf16x8  __attribute__((ext_vector_type(8)));
typedef short short4v __attribute__((ext_vector_type(4)));

#define AS1 __attribute__((address_space(1)))
#define AS3 __attribute__((address_space(3)))

__device__ __forceinline__ float silu_f(float x) { return x / (1.0f + __expf(-x)); }
__device__ __forceinline__ float softplus_f(float x) {
    return fmaxf(x, 0.0f) + log1pf(__expf(-fabsf(x)));
}
__device__ __forceinline__ unsigned short f2bf(float x) {
    unsigned int u = __float_as_uint(x);
    u += 0x7fffu + ((u >> 16) & 1u);           /* RNE */
    return (unsigned short)(u >> 16);
}
__device__ __forceinline__ float bf2f(unsigned short h) {
    return __uint_as_float(((unsigned int)h) << 16);
}

/* ---- weight pack. SEGS=2: [hi|hi] (pairs with act [hi|lo]).
        SEGS=3: [hi|lo|hi] (pairs with act [hi|hi|lo]).             ---- */
template<int SEGS>
__global__ __launch_bounds__(256) void wpack_kernel(
        const float* __restrict__ w, unsigned short* __restrict__ wp, int K) {
    int i = blockIdx.x * 256 + threadIdx.x;
    int kq = K >> 2;
    int row = i / kq;
    int c = (i - row * kq) << 2;
    float4 v = *(const float4*)(w + (size_t)row * K + c);
    short4v hi, lo;
    hi.x = f2bf(v.x); hi.y = f2bf(v.y); hi.z = f2bf(v.z); hi.w = f2bf(v.w);
    lo.x = f2bf(v.x - bf2f(hi.x)); lo.y = f2bf(v.y - bf2f(hi.y));
    lo.z = f2bf(v.z - bf2f(hi.z)); lo.w = f2bf(v.w - bf2f(hi.w));
    size_t b0 = (size_t)row * (SEGS * K) + c;
    if (SEGS == 2) {
        *(short4v*)(wp + b0)         = hi;
        *(short4v*)(wp + b0 + K)     = hi;
    } else {
        *(short4v*)(wp + b0)         = hi;
        *(short4v*)(wp + b0 + K)     = lo;
        *(short4v*)(wp + b0 + 2 * K) = hi;
    }
}

/* ---- RMSNorm + 2-seg act pack: x[row,1024] -> xn_p[row,2048]=[hi|lo] ---- */
__global__ __launch_bounds__(256) void rmsnorm_pack_kernel(
        const float* __restrict__ x, const float* __restrict__ w,
        unsigned short* __restrict__ xn_p) {
    int row = blockIdx.x;
    float4 v = ((const float4*)(x + (size_t)row * HIDDEN))[threadIdx.x];
    float ss = v.x*v.x + v.y*v.y + v.z*v.z + v.w*v.w;
    #pragma unroll
    for (int off = 32; off; off >>= 1) ss += __shfl_down(ss, off);
    __shared__ float wsum[4];
    if ((threadIdx.x & 63) == 0) wsum[threadIdx.x >> 6] = ss;
    __syncthreads();
    float scale = rsqrtf((wsum[0] + wsum[1] + wsum[2] + wsum[3]) / (float)HIDDEN + 1e-5f);
    float4 wv = ((const float4*)w)[threadIdx.x];
    float o0 = v.x * scale * wv.x, o1 = v.y * scale * wv.y;
    float o2 = v.z * scale * wv.z, o3 = v.w * scale * wv.w;
    short4v hi, lo;
    hi.x = f2bf(o0); hi.y = f2bf(o1); hi.z = f2bf(o2); hi.w = f2bf(o3);
    lo.x = f2bf(o0 - bf2f(hi.x)); lo.y = f2bf(o1 - bf2f(hi.y));
    lo.z = f2bf(o2 - bf2f(hi.z)); lo.w = f2bf(o3 - bf2f(hi.w));
    size_t b0 = (size_t)row * (2 * HIDDEN) + threadIdx.x * 4;
    *(short4v*)&xn_p[b0]          = hi;
    *(short4v*)&xn_p[b0 + HIDDEN] = lo;
}

/* ---- bf16 MFMA GEMM: 128x128 tile, BK=64, both-sides XOR-swizzled LDS ----
   C[M,N] = Ap[M,Kp] @ Wp[N,Kp]^T   (k in [z*klen,(z+1)*klen))
   EPI 0: col<splitN -> C0 else C1
   EPI 2: partial store to C0 + z*partStride
   EPI 3: softplus(v + bias[col]) -> C0                                  */
template<int EPI>
__global__ __launch_bounds__(256) void mgemm_kernel(
        const unsigned short* __restrict__ Ap, const unsigned short* __restrict__ Wp,
        int Kp, int klen, int brows, float* __restrict__ C0, float* __restrict__ C1,
        int splitN, int ldout, size_t partStride, const float* __restrict__ bias) {
    __shared__ short As[128 * 64];
    __shared__ short Bs[128 * 64];
    const int t = threadIdx.x;
    const int w = t >> 6, l = t & 63;
    const int m0 = blockIdx.y * 128, n0 = blockIdx.x * 128;
    const int kbeg = blockIdx.z * klen;
    const int wr = (w >> 1) * 64, wc = (w & 1) * 64;
    const int lrow = l & 15;
    f32x4 acc[4][4];
    #pragma unroll
    for (int m = 0; m < 4; ++m)
        #pragma unroll
        for (int n = 0; n < 4; ++n) {
            acc[m][n].x = 0.f; acc[m][n].y = 0.f; acc[m][n].z = 0.f; acc[m][n].w = 0.f;
        }
    const int srow = w * 32 + (l >> 3);
    const int sc8  = (l & 7) ^ ((l >> 3) & 7);
    const int brow = min(n0 + srow, brows - 1);   /* clamp for padded-N (x_proj) */
    const unsigned short* gaw = Ap + (size_t)(m0 + srow) * Kp + sc8 * 8;
    const unsigned short* gbw = Wp + (size_t)brow * Kp + sc8 * 8;
    for (int k0 = kbeg; k0 < kbeg + klen; k0 += 64) {
        __syncthreads();
        #pragma unroll
        for (int q = 0; q < 4; ++q) {
            __builtin_amdgcn_global_load_lds(
                (const AS1 unsigned int*)(gaw + k0 + (size_t)q * 8 * Kp),
                (AS3 unsigned int*)((char*)As + (w * 32 + q * 8) * 128), 16, 0, 0);
            __builtin_amdgcn_global_load_lds(
                (const AS1 unsigned int*)(gbw + k0 + (size_t)q * 8 * Kp),
                (AS3 unsigned int*)((char*)Bs + (w * 32 + q * 8) * 128), 16, 0, 0);
        }
        __syncthreads();
        #pragma unroll
        for (int kk = 0; kk < 2; ++kk) {
            const int slot = ((kk * 4 + (l >> 4)) ^ (l & 7)) * 8;
            bf16x8 af[4], bfr[4];
            #pragma unroll
            for (int m = 0; m < 4; ++m)
                af[m] = *(const bf16x8*)&As[(wr + m * 16 + lrow) * 64 + slot];
            #pragma unroll
            for (int n = 0; n < 4; ++n)
                bfr[n] = *(const bf16x8*)&Bs[(wc + n * 16 + lrow) * 64 + slot];
            #pragma unroll
            for (int m = 0; m < 4; ++m)
                #pragma unroll
                for (int n = 0; n < 4; ++n)
                    acc[m][n] = __builtin_amdgcn_mfma_f32_16x16x32_bf16(
                        af[m], bfr[n], acc[m][n], 0, 0, 0);
        }
    }
    float* dst = (EPI == 2) ? (C0 + blockIdx.z * partStride) : C0;
    #pragma unroll
    for (int m = 0; m < 4; ++m) {
        #pragma unroll
        for (int n = 0; n < 4; ++n) {
            #pragma unroll
            for (int j = 0; j < 4; ++j) {
                int row = m0 + wr + m * 16 + (l >> 4) * 4 + j;
                int col = n0 + wc + n * 16 + (l & 15);
                float v = acc[m][n][j];
                if (EPI == 0) {
                    if (col < splitN) C0[(size_t)row * ldout + col] = v;
                    else              C1[(size_t)row * ldout + (col - splitN)] = v;
                } else if (EPI == 2) {
                    dst[(size_t)row * ldout + col] = v;
                } else {
                    C0[(size_t)row * ldout + col] = softplus_f(v + bias[col]);
                }
            }
        }
    }
}

/* ---- reduce 4 split-K partials + residual x -> out (out_proj) ---- */
__global__ __launch_bounds__(256) void reduce4_kernel(
        const float* __restrict__ parts, size_t partStride,
        const float* __restrict__ x, float* __restrict__ out) {
    size_t i = (size_t)blockIdx.x * 256 + threadIdx.x;   /* float4 index */
    float4 a = ((const float4*)(parts))[i];
    float4 b = ((const float4*)(parts + partStride))[i];
    float4 c = ((const float4*)(parts + 2 * partStride))[i];
    float4 d = ((const float4*)(parts + 3 * partStride))[i];
    float4 xv = ((const float4*)x)[i];
    float4 o;
    o.x = a.x + b.x + c.x + d.x + xv.x;
    o.y = a.y + b.y + c.y + d.y + xv.y;
    o.z = a.z + b.z + c.z + d.z + xv.z;
    o.w = a.w + b.w + c.w + d.w + xv.w;
    ((float4*)out)[i] = o;
}

/* ---- reduce 4 x_proj partials -> xdbl fp32 [4096,96] + dtp_p 3-seg [4096,192] ---- */
__global__ __launch_bounds__(256) void reduceX_kernel(
        const float* __restrict__ parts, float* __restrict__ xdbl,
        unsigned short* __restrict__ dtp) {
    int i = blockIdx.x * 256 + threadIdx.x;      /* 4096*24 total */
    int row = i / 24;
    int c = (i - row * 24) * 4;
    float4 a = *(const float4*)(parts + (size_t)row * 128 + c);
    float4 b = *(const float4*)(parts + 524288 + (size_t)row * 128 + c);
    float4 d = *(const float4*)(parts + 2 * 524288 + (size_t)row * 128 + c);
    float4 e = *(const float4*)(parts + 3 * 524288 + (size_t)row * 128 + c);
    float4 s;
    s.x = a.x + b.x + d.x + e.x;
    s.y = a.y + b.y + d.y + e.y;
    s.z = a.z + b.z + d.z + e.z;
    s.w = a.w + b.w + d.w + e.w;
    *(float4*)(xdbl + (size_t)row * XDBL + c) = s;
    if (c < DT_RANK) {
        short4v hi, lo;
        hi.x = f2bf(s.x); hi.y = f2bf(s.y); hi.z = f2bf(s.z); hi.w = f2bf(s.w);
        lo.x = f2bf(s.x - bf2f(hi.x)); lo.y = f2bf(s.y - bf2f(hi.y));
        lo.z = f2bf(s.z - bf2f(hi.z)); lo.w = f2bf(s.w - bf2f(hi.w));
        size_t b0 = (size_t)row * 192 + c;
        *(short4v*)(dtp + b0)       = hi;
        *(short4v*)(dtp + b0 + 64)  = hi;
        *(short4v*)(dtp + b0 + 128) = lo;
    }
}

/* ---- causal depthwise conv (d_conv=4) + SiLU -> 3-seg packed xc ---- */
__global__ __launch_bounds__(256) void conv_silu_kernel(
        const float* __restrict__ xi, const float* __restrict__ w,
        const float* __restrict__ b, unsigned short* __restrict__ xc_p) {
    size_t i = (size_t)blockIdx.x * 256 + threadIdx.x;
    int d = (int)(i & (D_INNER - 1));
    int tt = (int)(i >> 11);
    int s = tt & (SEQ - 1);
    float4 wv = ((const float4*)w)[d];
    float acc = b[d];
    if (s >= 3) acc += wv.x * xi[i - 3 * D_INNER];
    if (s >= 2) acc += wv.y * xi[i - 2 * D_INNER];
    if (s >= 1) acc += wv.z * xi[i - 1 * D_INNER];
    acc += wv.w * xi[i];
    float o = silu_f(acc);
    unsigned short hi = f2bf(o);
    unsigned short lo = f2bf(o - bf2f(hi));
    size_t o6 = (size_t)tt * (3 * D_INNER) + d;
    xc_p[o6]               = hi;
    xc_p[o6 + D_INNER]     = hi;
    xc_p[o6 + 2 * D_INNER] = lo;
}

/* ==== selective scan: thread-per-(b,d,chunk), states in registers.
   u is reconstructed from packed xc (hi+lo).                        ==== */

__global__ __launch_bounds__(256) void scanA_kernel(
        const unsigned short* __restrict__ xcp, const float* __restrict__ delta,
        const float* __restrict__ xdbl, const float* __restrict__ A_log,
        float* __restrict__ hpart, float* __restrict__ Pp) {
    const int bid = blockIdx.x;            /* 512 blocks */
    const int b    = bid >> 8;
    const int c    = (bid >> 3) & 31;
    const int dblk = bid & 7;
    const int d    = (dblk << 8) + threadIdx.x;
    float adn[NSTATE];
    #pragma unroll
    for (int k = 0; k < 4; ++k) {
        float4 a = *(const float4*)(A_log + d * NSTATE + k * 4);
        adn[k*4+0] = -__expf(a.x); adn[k*4+1] = -__expf(a.y);
        adn[k*4+2] = -__expf(a.z); adn[k*4+3] = -__expf(a.w);
    }
    float h[NSTATE], P[NSTATE];
    #pragma unroll
    for (int n = 0; n < NSTATE; ++n) { h[n] = 0.f; P[n] = 1.f; }
    const int rowbase = b * SEQ + c * CHL;
    #pragma unroll 4
    for (int r = 0; r < CHL; ++r) {
        const int row = rowbase + r;
        const float* brow = xdbl + (size_t)row * XDBL + DT_RANK;  /* uniform addr */
        size_t o6 = (size_t)row * (3 * D_INNER) + d;
        float dl = delta[(size_t)row * D_INNER + d];
        float u  = bf2f(xcp[o6]) + bf2f(xcp[o6 + 2 * D_INNER]);
        float du = dl * u;
        #pragma unroll
        for (int n = 0; n < NSTATE; ++n) {
            float dA = __expf(dl * adn[n]);
            h[n] = fmaf(dA, h[n], du * brow[n]);
            P[n] *= dA;
        }
    }
    size_t base = (size_t)c * BDN + (size_t)(b * D_INNER + d) * NSTATE;
    #pragma unroll
    for (int k = 0; k < 4; ++k) {
        *(float4*)(hpart + base + k * 4) = make_float4(h[k*4], h[k*4+1], h[k*4+2], h[k*4+3]);
        *(float4*)(Pp    + base + k * 4) = make_float4(P[k*4], P[k*4+1], P[k*4+2], P[k*4+3]);
    }
}

__global__ __launch_bounds__(256) void scanB_kernel(
        const float* __restrict__ hpart, const float* __restrict__ Pp,
        float* __restrict__ hstart) {
    int idx = blockIdx.x * 256 + threadIdx.x;
    float h = 0.f;
    for (int c = 0; c < NCH; ++c) {
        hstart[(size_t)c * BDN + idx] = h;
        h = fmaf(Pp[(size_t)c * BDN + idx], h, hpart[(size_t)c * BDN + idx]);
    }
}

/* scanC: y_p aliases xcp (in-place over the packed-xc buffer).
   Safe: each (row,d) cell is owned by exactly one thread, and the writes
   data-depend on that thread's own reads of the same cell. NOTE: no
   __restrict__ on xcp / y_p.                                            */
__global__ __launch_bounds__(256) void scanC_kernel(
        const unsigned short* xcp, const float* __restrict__ delta,
        const float* __restrict__ xdbl, const float* __restrict__ A_log,
        const float* __restrict__ Dp, const float* __restrict__ hstart,
        const float* __restrict__ res, unsigned short* y_p) {
    const int bid = blockIdx.x;
    const int b    = bid >> 8;
    const int c    = (bid >> 3) & 31;
    const int dblk = bid & 7;
    const int d    = (dblk << 8) + threadIdx.x;
    float adn[NSTATE];
    #pragma unroll
    for (int k = 0; k < 4; ++k) {
        float4 a = *(const float4*)(A_log + d * NSTATE + k * 4);
        adn[k*4+0] = -__expf(a.x); adn[k*4+1] = -__expf(a.y);
        adn[k*4+2] = -__expf(a.z); adn[k*4+3] = -__expf(a.w);
    }
    const float Dd = Dp[d];
    float h[NSTATE];
    size_t base = (size_t)c * BDN + (size_t)(b * D_INNER + d) * NSTATE;
    #pragma unroll
    for (int k = 0; k < 4; ++k) {
        float4 hv = *(const float4*)(hstart + base + k * 4);
        h[k*4] = hv.x; h[k*4+1] = hv.y; h[k*4+2] = hv.z; h[k*4+3] = hv.w;
    }
    const int rowbase = b * SEQ + c * CHL;
    #pragma unroll 4
    for (int r = 0; r < CHL; ++r) {
        const int row = rowbase + r;
        const float* brow = xdbl + (size_t)row * XDBL + DT_RANK;       /* uniform */
        const float* crow = brow + NSTATE;                              /* uniform */
        size_t o6 = (size_t)row * (3 * D_INNER) + d;
        float dl = delta[(size_t)row * D_INNER + d];
        float u  = bf2f(xcp[o6]) + bf2f(xcp[o6 + 2 * D_INNER]);
        float du = dl * u;
        float ysum = u * Dd;
        #pragma unroll
        for (int n = 0; n < NSTATE; ++n) {
            float dA = __expf(dl * adn[n]);
            h[n] = fmaf(dA, h[n], du * brow[n]);
            ysum = fmaf(h[n], crow[n], ysum);
        }
        float rv = res[(size_t)row * D_INNER + d];
        float gv = ysum * silu_f(rv);
        unsigned short hi = f2bf(gv);
        unsigned short lo = f2bf(gv - bf2f(hi));
        y_p[o6]               = hi;
        y_p[o6 + D_INNER]     = hi;
        y_p[o6 + 2 * D_INNER] = lo;
    }
}

extern "C" void kernel_launch(void* const* d_in, const int* in_sizes, int n_in,
                              void* d_out, int out_size, void* d_ws, size_t ws_size,
                              hipStream_t stream) {
    const float* x         = (const float*)d_in[0];
    const float* norm_w    = (const float*)d_in[1];
    const float* in_proj_w = (const float*)d_in[2];
    const float* conv_w    = (const float*)d_in[3];
    const float* conv_b    = (const float*)d_in[4];
    const float* x_proj_w  = (const float*)d_in[5];
    const float* dt_proj_w = (const float*)d_in[6];
    const float* dt_proj_b = (const float*)d_in[7];
    const float* A_log     = (const float*)d_in[8];
    const float* Dp        = (const float*)d_in[9];
    const float* out_proj_w= (const float*)d_in[10];
    float* out = (float*)d_out;
    float* ws  = (float*)d_ws;

    const size_t M8 = (size_t)T_TOK * D_INNER;           /* 8388608 */
    float* res   = ws;                                    /* 8M fl; dead after scanC */
    float* delta = res + M8;                              /* 8M fl; dead after scanC */
    float* xdbl  = delta + M8;                            /* 393216 fl */
    unsigned short* xn_p   = (unsigned short*)(xdbl + (size_t)T_TOK * XDBL);
    unsigned short* w_in_p = xn_p   + (size_t)4096 * 2048;   /* 8M sh */
    unsigned short* w_out_p= w_in_p + (size_t)4096 * 2048;   /* 1024*6144 sh */
    unsigned short* w_xp_p = w_out_p+ (size_t)1024 * 6144;   /* 96*6144 sh */
    unsigned short* w_dt_p = w_xp_p + (size_t)96 * 6144;     /* 2048*192 sh */
    unsigned short* xc_p   = w_dt_p + (size_t)2048 * 192;    /* 4096*6144 sh */
    unsigned short* dtp_p  = xc_p   + (size_t)4096 * 6144;   /* 4096*192 sh */
    float* xi    = (float*)(dtp_p + (size_t)4096 * 192);     /* 8M fl */
    float* hpart = xi;                          /* xi dead after conv */
    float* Pp    = xi + (size_t)BDN * NCH;
    float* hstart= Pp + (size_t)BDN * NCH;
    float* parts_x = hstart + (size_t)BDN * NCH;             /* 4*524288 fl */
    unsigned short* y_p = xc_p;                 /* in-place over packed xc */
    float* parts = ws;                          /* res+delta region: 16M fl */
    const size_t partStride = (size_t)T_TOK * HIDDEN;        /* 4194304 */

    /* weight packs */
    wpack_kernel<2><<<4096, 256, 0, stream>>>(in_proj_w,  w_in_p,  HIDDEN);
    wpack_kernel<3><<<2048, 256, 0, stream>>>(out_proj_w, w_out_p, D_INNER);
    wpack_kernel<3><<<192,  256, 0, stream>>>(x_proj_w,   w_xp_p,  D_INNER);
    wpack_kernel<3><<<128,  256, 0, stream>>>(dt_proj_w,  w_dt_p,  DT_RANK);

    /* RMSNorm + 2-seg pack */
    rmsnorm_pack_kernel<<<T_TOK, 256, 0, stream>>>(x, norm_w, xn_p);

    { /* in_proj (2-seg split-bf16): [4096,2048]@[4096,2048]^T -> xi | res */
        dim3 g(4096 / 128, T_TOK / 128, 1);
        mgemm_kernel<0><<<g, 256, 0, stream>>>(xn_p, w_in_p, 2 * HIDDEN, 2 * HIDDEN,
                                               4096, xi, res, D_INNER, D_INNER, 0, nullptr);
    }

    /* conv + SiLU -> 3-seg packed xc */
    conv_silu_kernel<<<(int)(M8 / 256), 256, 0, stream>>>(xi, conv_w, conv_b, xc_p);

    { /* x_proj (3-seg, split-K=4, N padded 96->128): partials */
        dim3 g(1, T_TOK / 128, 4);
        mgemm_kernel<2><<<g, 256, 0, stream>>>(xc_p, w_xp_p, 3 * D_INNER, 6144 / 4,
                                               96, parts_x, nullptr, 0, 128, 524288, nullptr);
    }
    reduceX_kernel<<<T_TOK * 24 / 256, 256, 0, stream>>>(parts_x, xdbl, dtp_p);

    { /* dt_proj (3-seg) + bias + softplus -> delta */
        dim3 g(D_INNER / 128, T_TOK / 128, 1);
        mgemm_kernel<3><<<g, 256, 0, stream>>>(dtp_p, w_dt_p, 3 * DT_RANK, 3 * DT_RANK,
                                               D_INNER, delta, nullptr, 0, D_INNER, 0, dt_proj_b);
    }

    /* selective scan */
    scanA_kernel<<<512, 256, 0, stream>>>(xc_p, delta, xdbl, A_log, hpart, Pp);
    scanB_kernel<<<BDN / 256, 256, 0, stream>>>(hpart, Pp, hstart);
    scanC_kernel<<<512, 256, 0, stream>>>(xc_p, delta, xdbl, A_log, Dp, hstart, res, y_p);

    { /* out_proj (3-seg, split-K=4): partials */
        dim3 g(HIDDEN / 128, T_TOK / 128, 4);
        mgemm_kernel<2><<<g, 256, 0, stream>>>(y_p, w_out_p, 3 * D_INNER, 6144 / 4,
                                               HIDDEN, parts, nullptr, 0, HIDDEN, partStride, nullptr);
    }
    /* residual + reduce */
    reduce4_kernel<<<(int)(partStride / 4 / 256), 256, 0, stream>>>(parts, partStride, x, out);
}

// Round 6
// 361.115 us; speedup vs baseline: 3.5918x; 1.1002x over previous
//
#include <hip/hip_runtime.h>
#include <math.h>

#define HIDDEN   1024
#define D_INNER  2048
#define NSTATE   16
#define DT_RANK  64
#define BATCH    2
#define SEQ      2048
#define T_TOK    (BATCH * SEQ)            /* 4096 tokens */
#define XDBL     (DT_RANK + 2 * NSTATE)   /* 96 */
#define NCH      32                       /* scan chunks */
#define CHL      (SEQ / NCH)              /* 64 steps per chunk */
#define BDN      (BATCH * D_INNER * NSTATE) /* 65536 */

typedef float f32x4   __attribute__((ext_vector_type(4)));
typedef short bf16x8  __attribute__((ext_vector_type(8)));
typedef short short4v __attribute__((ext_vector_type(4)));

#define AS1 __attribute__((address_space(1)))
#define AS3 __attribute__((address_space(3)))
#define GLOAD(src, dst) __builtin_amdgcn_global_load_lds( \
    (const AS1 unsigned int*)(src), (AS3 unsigned int*)(dst), 16, 0, 0)

__device__ __forceinline__ float silu_f(float x) { return x / (1.0f + __expf(-x)); }
__device__ __forceinline__ float softplus_f(float x) {
    return fmaxf(x, 0.0f) + log1pf(__expf(-fabsf(x)));
}
__device__ __forceinline__ unsigned short f2bf(float x) {
    unsigned int u = __float_as_uint(x);
    u += 0x7fffu + ((u >> 16) & 1u);           /* RNE */
    return (unsigned short)(u >> 16);
}
__device__ __forceinline__ float bf2f(unsigned short h) {
    return __uint_as_float(((unsigned int)h) << 16);
}

/* ---- weight pack. SEGS=1: [hi] (stride K). SEGS=2: [hi|lo] (stride 2K). ---- */
template<int SEGS>
__global__ __launch_bounds__(256) void wpack_kernel(
        const float* __restrict__ w, unsigned short* __restrict__ wp, int K) {
    int i = blockIdx.x * 256 + threadIdx.x;
    int kq = K >> 2;
    int row = i / kq;
    int c = (i - row * kq) << 2;
    float4 v = *(const float4*)(w + (size_t)row * K + c);
    short4v hi, lo;
    hi.x = f2bf(v.x); hi.y = f2bf(v.y); hi.z = f2bf(v.z); hi.w = f2bf(v.w);
    lo.x = f2bf(v.x - bf2f(hi.x)); lo.y = f2bf(v.y - bf2f(hi.y));
    lo.z = f2bf(v.z - bf2f(hi.z)); lo.w = f2bf(v.w - bf2f(hi.w));
    size_t b0 = (size_t)row * (SEGS * K) + c;
    *(short4v*)(wp + b0) = hi;
    if (SEGS == 2) *(short4v*)(wp + b0 + K) = lo;
}

/* ---- RMSNorm + [hi|lo] act pack: x[row,1024] -> xn_p[row,2048] ---- */
__global__ __launch_bounds__(256) void rmsnorm_pack_kernel(
        const float* __restrict__ x, const float* __restrict__ w,
        unsigned short* __restrict__ xn_p) {
    int row = blockIdx.x;
    float4 v = ((const float4*)(x + (size_t)row * HIDDEN))[threadIdx.x];
    float ss = v.x*v.x + v.y*v.y + v.z*v.z + v.w*v.w;
    #pragma unroll
    for (int off = 32; off; off >>= 1) ss += __shfl_down(ss, off);
    __shared__ float wsum[4];
    if ((threadIdx.x & 63) == 0) wsum[threadIdx.x >> 6] = ss;
    __syncthreads();
    float scale = rsqrtf((wsum[0] + wsum[1] + wsum[2] + wsum[3]) / (float)HIDDEN + 1e-5f);
    float4 wv = ((const float4*)w)[threadIdx.x];
    float o0 = v.x * scale * wv.x, o1 = v.y * scale * wv.y;
    float o2 = v.z * scale * wv.z, o3 = v.w * scale * wv.w;
    short4v hi, lo;
    hi.x = f2bf(o0); hi.y = f2bf(o1); hi.z = f2bf(o2); hi.w = f2bf(o3);
    lo.x = f2bf(o0 - bf2f(hi.x)); lo.y = f2bf(o1 - bf2f(hi.y));
    lo.z = f2bf(o2 - bf2f(hi.z)); lo.w = f2bf(o3 - bf2f(hi.w));
    size_t b0 = (size_t)row * (2 * HIDDEN) + threadIdx.x * 4;
    *(short4v*)&xn_p[b0]          = hi;
    *(short4v*)&xn_p[b0 + HIDDEN] = lo;
}

/* ---- component-packed split-bf16 MFMA GEMM ----
   A stored [M][2*Klog] = [hi|lo]; W stored [N][2*Klog] (TERMS=3) or [N][Klog] (TERMS=2).
   TERMS=2: C = (Ah+Al)&middot;Wh   (2 MFMA / frag pair)
   TERMS=3: C = Ah·Wh + Ah·Wl + Al·Wh  (3 MFMA / frag pair)
   k in [z*klen, (z+1)*klen), logical.
   EPI 0: col<splitN -> C0 else C1
   EPI 2: partial store to C0 + z*partStride
   EPI 3: softplus(v + bias[col]) -> C0                                   */
template<int TERMS, int EPI>
__global__ __launch_bounds__(256) void mgemm_kernel(
        const unsigned short* __restrict__ Ap, const unsigned short* __restrict__ Wp,
        int Klog, int klen, int brows, float* __restrict__ C0, float* __restrict__ C1,
        int splitN, int ldout, size_t partStride, const float* __restrict__ bias) {
    constexpr int NT = (TERMS == 3) ? 4 : 3;
    __shared__ short lds[NT * 128 * 64];
    short* Ah = lds;
    short* Al = lds + 128 * 64;
    short* Bh = lds + 2 * 128 * 64;
    short* Bl = lds + 3 * 128 * 64;       /* used only if TERMS==3 */
    const int t = threadIdx.x;
    const int w = t >> 6, l = t & 63;
    const int m0 = blockIdx.y * 128, n0 = blockIdx.x * 128;
    const int kbeg = blockIdx.z * klen;
    const int wr = (w >> 1) * 64, wc = (w & 1) * 64;
    const int lrow = l & 15;
    f32x4 acc[4][4];
    #pragma unroll
    for (int m = 0; m < 4; ++m)
        #pragma unroll
        for (int n = 0; n < 4; ++n) {
            acc[m][n].x = 0.f; acc[m][n].y = 0.f; acc[m][n].z = 0.f; acc[m][n].w = 0.f;
        }
    const int Asr = 2 * Klog;
    const int Wsr = (TERMS == 3) ? 2 * Klog : Klog;
    const int srow = w * 32 + (l >> 3);
    const int sc8  = (l & 7) ^ ((l >> 3) & 7);
    const int brow = min(n0 + srow, brows - 1);   /* clamp for padded-N */
    const unsigned short* ga = Ap + (size_t)(m0 + srow) * Asr + sc8 * 8;
    const unsigned short* gb = Wp + (size_t)brow * Wsr + sc8 * 8;
    const int ldsoff = (w * 32 + (l >> 3) * 0) * 0;  /* (kept simple below) */
    (void)ldsoff;
    for (int k0 = kbeg; k0 < kbeg + klen; k0 += 64) {
        __syncthreads();
        #pragma unroll
        for (int q = 0; q < 4; ++q) {
            const int doff = (w * 32 + q * 8) * 128;   /* byte offset in each tile */
            GLOAD(ga + k0 + (size_t)q * 8 * Asr,        (char*)Ah + doff);
            GLOAD(ga + Klog + k0 + (size_t)q * 8 * Asr, (char*)Al + doff);
            GLOAD(gb + k0 + (size_t)q * 8 * Wsr,        (char*)Bh + doff);
            if (TERMS == 3)
                GLOAD(gb + Klog + k0 + (size_t)q * 8 * Wsr, (char*)Bl + doff);
        }
        __syncthreads();
        #pragma unroll
        for (int kk = 0; kk < 2; ++kk) {
            const int slot = ((kk * 4 + (l >> 4)) ^ (l & 7)) * 8;
            bf16x8 ah[4], al[4], bh[4], bl[4];
            #pragma unroll
            for (int m = 0; m < 4; ++m) {
                ah[m] = *(const bf16x8*)&Ah[(wr + m * 16 + lrow) * 64 + slot];
                al[m] = *(const bf16x8*)&Al[(wr + m * 16 + lrow) * 64 + slot];
            }
            #pragma unroll
            for (int n = 0; n < 4; ++n) {
                bh[n] = *(const bf16x8*)&Bh[(wc + n * 16 + lrow) * 64 + slot];
                if (TERMS == 3)
                    bl[n] = *(const bf16x8*)&Bl[(wc + n * 16 + lrow) * 64 + slot];
            }
            #pragma unroll
            for (int m = 0; m < 4; ++m)
                #pragma unroll
                for (int n = 0; n < 4; ++n) {
                    acc[m][n] = __builtin_amdgcn_mfma_f32_16x16x32_bf16(
                        ah[m], bh[n], acc[m][n], 0, 0, 0);
                    acc[m][n] = __builtin_amdgcn_mfma_f32_16x16x32_bf16(
                        al[m], bh[n], acc[m][n], 0, 0, 0);
                    if (TERMS == 3)
                        acc[m][n] = __builtin_amdgcn_mfma_f32_16x16x32_bf16(
                            ah[m], bl[n], acc[m][n], 0, 0, 0);
                }
        }
    }
    float* dst = (EPI == 2) ? (C0 + blockIdx.z * partStride) : C0;
    #pragma unroll
    for (int m = 0; m < 4; ++m) {
        #pragma unroll
        for (int n = 0; n < 4; ++n) {
            #pragma unroll
            for (int j = 0; j < 4; ++j) {
                int row = m0 + wr + m * 16 + (l >> 4) * 4 + j;
                int col = n0 + wc + n * 16 + (l & 15);
                float v = acc[m][n][j];
                if (EPI == 0) {
                    if (col < splitN) C0[(size_t)row * ldout + col] = v;
                    else              C1[(size_t)row * ldout + (col - splitN)] = v;
                } else if (EPI == 2) {
                    dst[(size_t)row * ldout + col] = v;
                } else {
                    C0[(size_t)row * ldout + col] = softplus_f(v + bias[col]);
                }
            }
        }
    }
}

/* ---- reduce 4 split-K partials + residual x -> out (out_proj) ---- */
__global__ __launch_bounds__(256) void reduce4_kernel(
        const float* __restrict__ parts, size_t partStride,
        const float* __restrict__ x, float* __restrict__ out) {
    size_t i = (size_t)blockIdx.x * 256 + threadIdx.x;   /* float4 index */
    float4 a = ((const float4*)(parts))[i];
    float4 b = ((const float4*)(parts + partStride))[i];
    float4 c = ((const float4*)(parts + 2 * partStride))[i];
    float4 d = ((const float4*)(parts + 3 * partStride))[i];
    float4 xv = ((const float4*)x)[i];
    float4 o;
    o.x = a.x + b.x + c.x + d.x + xv.x;
    o.y = a.y + b.y + c.y + d.y + xv.y;
    o.z = a.z + b.z + c.z + d.z + xv.z;
    o.w = a.w + b.w + c.w + d.w + xv.w;
    ((float4*)out)[i] = o;
}

/* ---- reduce 4 x_proj partials -> xdbl fp32 [4096,96] + dtp_p [hi|lo] [4096,128] ---- */
__global__ __launch_bounds__(256) void reduceX_kernel(
        const float* __restrict__ parts, float* __restrict__ xdbl,
        unsigned short* __restrict__ dtp) {
    int i = blockIdx.x * 256 + threadIdx.x;      /* 4096*24 total */
    int row = i / 24;
    int c = (i - row * 24) * 4;
    float4 a = *(const float4*)(parts + (size_t)row * 128 + c);
    float4 b = *(const float4*)(parts + 524288 + (size_t)row * 128 + c);
    float4 d = *(const float4*)(parts + 2 * 524288 + (size_t)row * 128 + c);
    float4 e = *(const float4*)(parts + 3 * 524288 + (size_t)row * 128 + c);
    float4 s;
    s.x = a.x + b.x + d.x + e.x;
    s.y = a.y + b.y + d.y + e.y;
    s.z = a.z + b.z + d.z + e.z;
    s.w = a.w + b.w + d.w + e.w;
    *(float4*)(xdbl + (size_t)row * XDBL + c) = s;
    if (c < DT_RANK) {
        short4v hi, lo;
        hi.x = f2bf(s.x); hi.y = f2bf(s.y); hi.z = f2bf(s.z); hi.w = f2bf(s.w);
        lo.x = f2bf(s.x - bf2f(hi.x)); lo.y = f2bf(s.y - bf2f(hi.y));
        lo.z = f2bf(s.z - bf2f(hi.z)); lo.w = f2bf(s.w - bf2f(hi.w));
        size_t b0 = (size_t)row * 128 + c;
        *(short4v*)(dtp + b0)      = hi;
        *(short4v*)(dtp + b0 + 64) = lo;
    }
}

/* ---- causal depthwise conv (d_conv=4) + SiLU -> [hi|lo] packed xc ---- */
__global__ __launch_bounds__(256) void conv_silu_kernel(
        const float* __restrict__ xi, const float* __restrict__ w,
        const float* __restrict__ b, unsigned short* __restrict__ xc_p) {
    size_t i = (size_t)blockIdx.x * 256 + threadIdx.x;
    int d = (int)(i & (D_INNER - 1));
    int tt = (int)(i >> 11);
    int s = tt & (SEQ - 1);
    float4 wv = ((const float4*)w)[d];
    float acc = b[d];
    if (s >= 3) acc += wv.x * xi[i - 3 * D_INNER];
    if (s >= 2) acc += wv.y * xi[i - 2 * D_INNER];
    if (s >= 1) acc += wv.z * xi[i - 1 * D_INNER];
    acc += wv.w * xi[i];
    float o = silu_f(acc);
    unsigned short hi = f2bf(o);
    unsigned short lo = f2bf(o - bf2f(hi));
    size_t o2 = (size_t)tt * (2 * D_INNER) + d;
    xc_p[o2]           = hi;
    xc_p[o2 + D_INNER] = lo;
}

/* ==== selective scan: thread-per-(b,d,chunk), states in registers.
   u reconstructed from packed xc (hi+lo). B/C rows are wave-uniform. ==== */

__global__ __launch_bounds__(256) void scanA_kernel(
        const unsigned short* __restrict__ xcp, const float* __restrict__ delta,
        const float* __restrict__ xdbl, const float* __restrict__ A_log,
        float* __restrict__ hpart, float* __restrict__ Pp) {
    const int bid = blockIdx.x;            /* 512 blocks */
    const int b    = bid >> 8;
    const int c    = (bid >> 3) & 31;
    const int dblk = bid & 7;
    const int d    = (dblk << 8) + threadIdx.x;
    float adn[NSTATE];
    #pragma unroll
    for (int k = 0; k < 4; ++k) {
        float4 a = *(const float4*)(A_log + d * NSTATE + k * 4);
        adn[k*4+0] = -__expf(a.x); adn[k*4+1] = -__expf(a.y);
        adn[k*4+2] = -__expf(a.z); adn[k*4+3] = -__expf(a.w);
    }
    float h[NSTATE], P[NSTATE];
    #pragma unroll
    for (int n = 0; n < NSTATE; ++n) { h[n] = 0.f; P[n] = 1.f; }
    const int rowbase = b * SEQ + c * CHL;
    #pragma unroll 4
    for (int r = 0; r < CHL; ++r) {
        const int row = rowbase + r;
        const float* brow = xdbl + (size_t)row * XDBL + DT_RANK;  /* uniform addr */
        size_t o2 = (size_t)row * (2 * D_INNER) + d;
        float dl = delta[(size_t)row * D_INNER + d];
        float u  = bf2f(xcp[o2]) + bf2f(xcp[o2 + D_INNER]);
        float du = dl * u;
        #pragma unroll
        for (int n = 0; n < NSTATE; ++n) {
            float dA = __expf(dl * adn[n]);
            h[n] = fmaf(dA, h[n], du * brow[n]);
            P[n] *= dA;
        }
    }
    size_t base = (size_t)c * BDN + (size_t)(b * D_INNER + d) * NSTATE;
    #pragma unroll
    for (int k = 0; k < 4; ++k) {
        *(float4*)(hpart + base + k * 4) = make_float4(h[k*4], h[k*4+1], h[k*4+2], h[k*4+3]);
        *(float4*)(Pp    + base + k * 4) = make_float4(P[k*4], P[k*4+1], P[k*4+2], P[k*4+3]);
    }
}

__global__ __launch_bounds__(256) void scanB_kernel(
        const float* __restrict__ hpart, const float* __restrict__ Pp,
        float* __restrict__ hstart) {
    int idx = blockIdx.x * 256 + threadIdx.x;
    float h = 0.f;
    for (int c = 0; c < NCH; ++c) {
        hstart[(size_t)c * BDN + idx] = h;
        h = fmaf(Pp[(size_t)c * BDN + idx], h, hpart[(size_t)c * BDN + idx]);
    }
}

/* scanC: y_p aliases xcp (in-place over the packed-xc buffer).
   Safe: each (row,d) cell pair is owned by exactly one thread, and the
   writes data-depend on that thread's own reads of the same cells.      */
__global__ __launch_bounds__(256) void scanC_kernel(
        const unsigned short* xcp, const float* __restrict__ delta,
        const float* __restrict__ xdbl, const float* __restrict__ A_log,
        const float* __restrict__ Dp, const float* __restrict__ hstart,
        const float* __restrict__ res, unsigned short* y_p) {
    const int bid = blockIdx.x;
    const int b    = bid >> 8;
    const int c    = (bid >> 3) & 31;
    const int dblk = bid & 7;
    const int d    = (dblk << 8) + threadIdx.x;
    float adn[NSTATE];
    #pragma unroll
    for (int k = 0; k < 4; ++k) {
        float4 a = *(const float4*)(A_log + d * NSTATE + k * 4);
        adn[k*4+0] = -__expf(a.x); adn[k*4+1] = -__expf(a.y);
        adn[k*4+2] = -__expf(a.z); adn[k*4+3] = -__expf(a.w);
    }
    const float Dd = Dp[d];
    float h[NSTATE];
    size_t base = (size_t)c * BDN + (size_t)(b * D_INNER + d) * NSTATE;
    #pragma unroll
    for (int k = 0; k < 4; ++k) {
        float4 hv = *(const float4*)(hstart + base + k * 4);
        h[k*4] = hv.x; h[k*4+1] = hv.y; h[k*4+2] = hv.z; h[k*4+3] = hv.w;
    }
    const int rowbase = b * SEQ + c * CHL;
    #pragma unroll 4
    for (int r = 0; r < CHL; ++r) {
        const int row = rowbase + r;
        const float* brow = xdbl + (size_t)row * XDBL + DT_RANK;       /* uniform */
        const float* crow = brow + NSTATE;                              /* uniform */
        size_t o2 = (size_t)row * (2 * D_INNER) + d;
        float dl = delta[(size_t)row * D_INNER + d];
        float u  = bf2f(xcp[o2]) + bf2f(xcp[o2 + D_INNER]);
        float du = dl * u;
        float ysum = u * Dd;
        #pragma unroll
        for (int n = 0; n < NSTATE; ++n) {
            float dA = __expf(dl * adn[n]);
            h[n] = fmaf(dA, h[n], du * brow[n]);
            ysum = fmaf(h[n], crow[n], ysum);
        }
        float rv = res[(size_t)row * D_INNER + d];
        float gv = ysum * silu_f(rv);
        unsigned short hi = f2bf(gv);
        unsigned short lo = f2bf(gv - bf2f(hi));
        y_p[o2]           = hi;
        y_p[o2 + D_INNER] = lo;
    }
}

extern "C" void kernel_launch(void* const* d_in, const int* in_sizes, int n_in,
                              void* d_out, int out_size, void* d_ws, size_t ws_size,
                              hipStream_t stream) {
    const float* x         = (const float*)d_in[0];
    const float* norm_w    = (const float*)d_in[1];
    const float* in_proj_w = (const float*)d_in[2];
    const float* conv_w    = (const float*)d_in[3];
    const float* conv_b    = (const float*)d_in[4];
    const float* x_proj_w  = (const float*)d_in[5];
    const float* dt_proj_w = (const float*)d_in[6];
    const float* dt_proj_b = (const float*)d_in[7];
    const float* A_log     = (const float*)d_in[8];
    const float* Dp        = (const float*)d_in[9];
    const float* out_proj_w= (const float*)d_in[10];
    float* out = (float*)d_out;
    float* ws  = (float*)d_ws;

    const size_t M8 = (size_t)T_TOK * D_INNER;           /* 8388608 */
    float* res   = ws;                                    /* 8M fl; dead after scanC */
    float* delta = res + M8;                              /* 8M fl; dead after scanC */
    float* xdbl  = delta + M8;                            /* 393216 fl */
    unsigned short* xn_p   = (unsigned short*)(xdbl + (size_t)T_TOK * XDBL);
    unsigned short* w_in_p = xn_p   + (size_t)4096 * 2048;   /* 4096x1024 sh */
    unsigned short* w_out_p= w_in_p + (size_t)4096 * 1024;   /* 1024x4096 sh */
    unsigned short* w_xp_p = w_out_p+ (size_t)1024 * 4096;   /* 96x4096 sh */
    unsigned short* w_dt_p = w_xp_p + (size_t)96 * 4096;     /* 2048x128 sh */
    unsigned short* xc_p   = w_dt_p + (size_t)2048 * 128;    /* 4096x4096 sh */
    unsigned short* dtp_p  = xc_p   + (size_t)4096 * 4096;   /* 4096x128 sh */
    float* xi    = (float*)(dtp_p + (size_t)4096 * 128);     /* 8M fl */
    float* hpart = xi;                          /* xi dead after conv */
    float* Pp    = xi + (size_t)BDN * NCH;
    float* hstart= Pp + (size_t)BDN * NCH;
    float* parts_x = hstart + (size_t)BDN * NCH;             /* 4*524288 fl */
    unsigned short* y_p = xc_p;                 /* in-place over packed xc */
    float* parts = ws;                          /* res+delta region: 16M fl */
    const size_t partStride = (size_t)T_TOK * HIDDEN;        /* 4194304 */

    /* weight packs */
    wpack_kernel<1><<<4096, 256, 0, stream>>>(in_proj_w,  w_in_p,  HIDDEN);
    wpack_kernel<2><<<2048, 256, 0, stream>>>(out_proj_w, w_out_p, D_INNER);
    wpack_kernel<2><<<192,  256, 0, stream>>>(x_proj_w,   w_xp_p,  D_INNER);
    wpack_kernel<2><<<128,  256, 0, stream>>>(dt_proj_w,  w_dt_p,  DT_RANK);

    /* RMSNorm + [hi|lo] pack */
    rmsnorm_pack_kernel<<<T_TOK, 256, 0, stream>>>(x, norm_w, xn_p);

    { /* in_proj (2-term): [4096,1024]@[4096,1024]^T -> xi | res */
        dim3 g(4096 / 128, T_TOK / 128, 1);
        mgemm_kernel<2, 0><<<g, 256, 0, stream>>>(xn_p, w_in_p, HIDDEN, HIDDEN,
                                                  4096, xi, res, D_INNER, D_INNER, 0, nullptr);
    }

    /* conv + SiLU -> [hi|lo] packed xc */
    conv_silu_kernel<<<(int)(M8 / 256), 256, 0, stream>>>(xi, conv_w, conv_b, xc_p);

    { /* x_proj (3-term, split-K=4, N padded 96->128): partials */
        dim3 g(1, T_TOK / 128, 4);
        mgemm_kernel<3, 2><<<g, 256, 0, stream>>>(xc_p, w_xp_p, D_INNER, D_INNER / 4,
                                                  96, parts_x, nullptr, 0, 128, 524288, nullptr);
    }
    reduceX_kernel<<<T_TOK * 24 / 256, 256, 0, stream>>>(parts_x, xdbl, dtp_p);

    { /* dt_proj (3-term) + bias + softplus -> delta */
        dim3 g(D_INNER / 128, T_TOK / 128, 1);
        mgemm_kernel<3, 3><<<g, 256, 0, stream>>>(dtp_p, w_dt_p, DT_RANK, DT_RANK,
                                                  D_INNER, delta, nullptr, 0, D_INNER, 0, dt_proj_b);
    }

    /* selective scan */
    scanA_kernel<<<512, 256, 0, stream>>>(xc_p, delta, xdbl, A_log, hpart, Pp);
    scanB_kernel<<<BDN / 256, 256, 0, stream>>>(hpart, Pp, hstart);
    scanC_kernel<<<512, 256, 0, stream>>>(xc_p, delta, xdbl, A_log, Dp, hstart, res, y_p);

    { /* out_proj (3-term, split-K=4): partials */
        dim3 g(HIDDEN / 128, T_TOK / 128, 4);
        mgemm_kernel<3, 2><<<g, 256, 0, stream>>>(y_p, w_out_p, D_INNER, D_INNER / 4,
                                                  HIDDEN, parts, nullptr, 0, HIDDEN, partStride, nullptr);
    }
    /* residual + reduce */
    reduce4_kernel<<<(int)(partStride / 4 / 256), 256, 0, stream>>>(parts, partStride, x, out);
}

// Round 7
// 336.172 us; speedup vs baseline: 3.8583x; 1.0742x over previous
//
#include <hip/hip_runtime.h>
#include <math.h>

#define HIDDEN   1024
#define D_INNER  2048
#define NSTATE   16
#define DT_RANK  64
#define BATCH    2
#define SEQ      2048
#define T_TOK    (BATCH * SEQ)            /* 4096 tokens */
#define XDBL     (DT_RANK + 2 * NSTATE)   /* 96 */
#define NCH      64                       /* scan chunks */
#define CHL      (SEQ / NCH)              /* 32 steps per chunk */
#define BDN      (BATCH * D_INNER * NSTATE) /* 65536 */

typedef float f32x4   __attribute__((ext_vector_type(4)));
typedef short bf16x8  __attribute__((ext_vector_type(8)));
typedef short short4v __attribute__((ext_vector_type(4)));

#define AS1 __attribute__((address_space(1)))
#define AS3 __attribute__((address_space(3)))
#define GLOAD(src, dst) __builtin_amdgcn_global_load_lds( \
    (const AS1 unsigned int*)(src), (AS3 unsigned int*)(dst), 16, 0, 0)

__device__ __forceinline__ float silu_f(float x) { return x / (1.0f + __expf(-x)); }
__device__ __forceinline__ float softplus_f(float x) {
    return fmaxf(x, 0.0f) + log1pf(__expf(-fabsf(x)));
}
__device__ __forceinline__ unsigned short f2bf(float x) {
    unsigned int u = __float_as_uint(x);
    u += 0x7fffu + ((u >> 16) & 1u);           /* RNE */
    return (unsigned short)(u >> 16);
}
__device__ __forceinline__ float bf2f(unsigned short h) {
    return __uint_as_float(((unsigned int)h) << 16);
}

/* ---- weight pack. SEGS=1: [hi] (stride K). SEGS=2: [hi|lo] (stride 2K). ---- */
template<int SEGS>
__global__ __launch_bounds__(256) void wpack_kernel(
        const float* __restrict__ w, unsigned short* __restrict__ wp, int K) {
    int i = blockIdx.x * 256 + threadIdx.x;
    int kq = K >> 2;
    int row = i / kq;
    int c = (i - row * kq) << 2;
    float4 v = *(const float4*)(w + (size_t)row * K + c);
    short4v hi, lo;
    hi.x = f2bf(v.x); hi.y = f2bf(v.y); hi.z = f2bf(v.z); hi.w = f2bf(v.w);
    lo.x = f2bf(v.x - bf2f(hi.x)); lo.y = f2bf(v.y - bf2f(hi.y));
    lo.z = f2bf(v.z - bf2f(hi.z)); lo.w = f2bf(v.w - bf2f(hi.w));
    size_t b0 = (size_t)row * (SEGS * K) + c;
    *(short4v*)(wp + b0) = hi;
    if (SEGS == 2) *(short4v*)(wp + b0 + K) = lo;
}

/* ---- RMSNorm + [hi|lo] act pack: x[row,1024] -> xn_p[row,2048] ---- */
__global__ __launch_bounds__(256) void rmsnorm_pack_kernel(
        const float* __restrict__ x, const float* __restrict__ w,
        unsigned short* __restrict__ xn_p) {
    int row = blockIdx.x;
    float4 v = ((const float4*)(x + (size_t)row * HIDDEN))[threadIdx.x];
    float ss = v.x*v.x + v.y*v.y + v.z*v.z + v.w*v.w;
    #pragma unroll
    for (int off = 32; off; off >>= 1) ss += __shfl_down(ss, off);
    __shared__ float wsum[4];
    if ((threadIdx.x & 63) == 0) wsum[threadIdx.x >> 6] = ss;
    __syncthreads();
    float scale = rsqrtf((wsum[0] + wsum[1] + wsum[2] + wsum[3]) / (float)HIDDEN + 1e-5f);
    float4 wv = ((const float4*)w)[threadIdx.x];
    float o0 = v.x * scale * wv.x, o1 = v.y * scale * wv.y;
    float o2 = v.z * scale * wv.z, o3 = v.w * scale * wv.w;
    short4v hi, lo;
    hi.x = f2bf(o0); hi.y = f2bf(o1); hi.z = f2bf(o2); hi.w = f2bf(o3);
    lo.x = f2bf(o0 - bf2f(hi.x)); lo.y = f2bf(o1 - bf2f(hi.y));
    lo.z = f2bf(o2 - bf2f(hi.z)); lo.w = f2bf(o3 - bf2f(hi.w));
    size_t b0 = (size_t)row * (2 * HIDDEN) + threadIdx.x * 4;
    *(short4v*)&xn_p[b0]          = hi;
    *(short4v*)&xn_p[b0 + HIDDEN] = lo;
}

/* ---- component-packed split-bf16 MFMA GEMM ----
   A stored [M][2*Klog] = [hi|lo]; W stored [N][2*Klog] (TERMS=3) or [N][Klog] (TERMS=2).
   TERMS=2: C = (Ah+Al)·Wh   TERMS=3: C = Ah·Wh + Ah·Wl + Al·Wh
   EPI 0: col<splitN -> C0 else C1
   EPI 2: partial store to C0 + z*partStride
   EPI 3: softplus(v + bias[col]) -> C0                                   */
template<int TERMS, int EPI>
__global__ __launch_bounds__(256) void mgemm_kernel(
        const unsigned short* __restrict__ Ap, const unsigned short* __restrict__ Wp,
        int Klog, int klen, int brows, float* __restrict__ C0, float* __restrict__ C1,
        int splitN, int ldout, size_t partStride, const float* __restrict__ bias) {
    constexpr int NT = (TERMS == 3) ? 4 : 3;
    __shared__ short lds[NT * 128 * 64];
    short* Ah = lds;
    short* Al = lds + 128 * 64;
    short* Bh = lds + 2 * 128 * 64;
    short* Bl = lds + 3 * 128 * 64;       /* used only if TERMS==3 */
    const int t = threadIdx.x;
    const int w = t >> 6, l = t & 63;
    const int m0 = blockIdx.y * 128, n0 = blockIdx.x * 128;
    const int kbeg = blockIdx.z * klen;
    const int wr = (w >> 1) * 64, wc = (w & 1) * 64;
    const int lrow = l & 15;
    f32x4 acc[4][4];
    #pragma unroll
    for (int m = 0; m < 4; ++m)
        #pragma unroll
        for (int n = 0; n < 4; ++n) {
            acc[m][n].x = 0.f; acc[m][n].y = 0.f; acc[m][n].z = 0.f; acc[m][n].w = 0.f;
        }
    const int Asr = 2 * Klog;
    const int Wsr = (TERMS == 3) ? 2 * Klog : Klog;
    const int srow = w * 32 + (l >> 3);
    const int sc8  = (l & 7) ^ ((l >> 3) & 7);
    const int brow = min(n0 + srow, brows - 1);   /* clamp for padded-N */
    const unsigned short* ga = Ap + (size_t)(m0 + srow) * Asr + sc8 * 8;
    const unsigned short* gb = Wp + (size_t)brow * Wsr + sc8 * 8;
    for (int k0 = kbeg; k0 < kbeg + klen; k0 += 64) {
        __syncthreads();
        #pragma unroll
        for (int q = 0; q < 4; ++q) {
            const int doff = (w * 32 + q * 8) * 128;   /* byte offset in each tile */
            GLOAD(ga + k0 + (size_t)q * 8 * Asr,        (char*)Ah + doff);
            GLOAD(ga + Klog + k0 + (size_t)q * 8 * Asr, (char*)Al + doff);
            GLOAD(gb + k0 + (size_t)q * 8 * Wsr,        (char*)Bh + doff);
            if (TERMS == 3)
                GLOAD(gb + Klog + k0 + (size_t)q * 8 * Wsr, (char*)Bl + doff);
        }
        __syncthreads();
        #pragma unroll
        for (int kk = 0; kk < 2; ++kk) {
            const int slot = ((kk * 4 + (l >> 4)) ^ (l & 7)) * 8;
            bf16x8 ah[4], al[4], bh[4], bl[4];
            #pragma unroll
            for (int m = 0; m < 4; ++m) {
                ah[m] = *(const bf16x8*)&Ah[(wr + m * 16 + lrow) * 64 + slot];
                al[m] = *(const bf16x8*)&Al[(wr + m * 16 + lrow) * 64 + slot];
            }
            #pragma unroll
            for (int n = 0; n < 4; ++n) {
                bh[n] = *(const bf16x8*)&Bh[(wc + n * 16 + lrow) * 64 + slot];
                if (TERMS == 3)
                    bl[n] = *(const bf16x8*)&Bl[(wc + n * 16 + lrow) * 64 + slot];
            }
            #pragma unroll
            for (int m = 0; m < 4; ++m)
                #pragma unroll
                for (int n = 0; n < 4; ++n) {
                    acc[m][n] = __builtin_amdgcn_mfma_f32_16x16x32_bf16(
                        ah[m], bh[n], acc[m][n], 0, 0, 0);
                    acc[m][n] = __builtin_amdgcn_mfma_f32_16x16x32_bf16(
                        al[m], bh[n], acc[m][n], 0, 0, 0);
                    if (TERMS == 3)
                        acc[m][n] = __builtin_amdgcn_mfma_f32_16x16x32_bf16(
                            ah[m], bl[n], acc[m][n], 0, 0, 0);
                }
        }
    }
    float* dst = (EPI == 2) ? (C0 + blockIdx.z * partStride) : C0;
    #pragma unroll
    for (int m = 0; m < 4; ++m) {
        #pragma unroll
        for (int n = 0; n < 4; ++n) {
            #pragma unroll
            for (int j = 0; j < 4; ++j) {
                int row = m0 + wr + m * 16 + (l >> 4) * 4 + j;
                int col = n0 + wc + n * 16 + (l & 15);
                float v = acc[m][n][j];
                if (EPI == 0) {
                    if (col < splitN) C0[(size_t)row * ldout + col] = v;
                    else              C1[(size_t)row * ldout + (col - splitN)] = v;
                } else if (EPI == 2) {
                    dst[(size_t)row * ldout + col] = v;
                } else {
                    C0[(size_t)row * ldout + col] = softplus_f(v + bias[col]);
                }
            }
        }
    }
}

/* ---- reduce 4 split-K partials + residual x -> out (out_proj) ---- */
__global__ __launch_bounds__(256) void reduce4_kernel(
        const float* __restrict__ parts, size_t partStride,
        const float* __restrict__ x, float* __restrict__ out) {
    size_t i = (size_t)blockIdx.x * 256 + threadIdx.x;   /* float4 index */
    float4 a = ((const float4*)(parts))[i];
    float4 b = ((const float4*)(parts + partStride))[i];
    float4 c = ((const float4*)(parts + 2 * partStride))[i];
    float4 d = ((const float4*)(parts + 3 * partStride))[i];
    float4 xv = ((const float4*)x)[i];
    float4 o;
    o.x = a.x + b.x + c.x + d.x + xv.x;
    o.y = a.y + b.y + c.y + d.y + xv.y;
    o.z = a.z + b.z + c.z + d.z + xv.z;
    o.w = a.w + b.w + c.w + d.w + xv.w;
    ((float4*)out)[i] = o;
}

/* ---- reduce 4 x_proj partials -> xdbl fp32 [4096,96] + dtp_p [hi|lo] [4096,128] ---- */
__global__ __launch_bounds__(256) void reduceX_kernel(
        const float* __restrict__ parts, float* __restrict__ xdbl,
        unsigned short* __restrict__ dtp) {
    int i = blockIdx.x * 256 + threadIdx.x;      /* 4096*24 total */
    int row = i / 24;
    int c = (i - row * 24) * 4;
    float4 a = *(const float4*)(parts + (size_t)row * 128 + c);
    float4 b = *(const float4*)(parts + 524288 + (size_t)row * 128 + c);
    float4 d = *(const float4*)(parts + 2 * 524288 + (size_t)row * 128 + c);
    float4 e = *(const float4*)(parts + 3 * 524288 + (size_t)row * 128 + c);
    float4 s;
    s.x = a.x + b.x + d.x + e.x;
    s.y = a.y + b.y + d.y + e.y;
    s.z = a.z + b.z + d.z + e.z;
    s.w = a.w + b.w + d.w + e.w;
    *(float4*)(xdbl + (size_t)row * XDBL + c) = s;
    if (c < DT_RANK) {
        short4v hi, lo;
        hi.x = f2bf(s.x); hi.y = f2bf(s.y); hi.z = f2bf(s.z); hi.w = f2bf(s.w);
        lo.x = f2bf(s.x - bf2f(hi.x)); lo.y = f2bf(s.y - bf2f(hi.y));
        lo.z = f2bf(s.z - bf2f(hi.z)); lo.w = f2bf(s.w - bf2f(hi.w));
        size_t b0 = (size_t)row * 128 + c;
        *(short4v*)(dtp + b0)      = hi;
        *(short4v*)(dtp + b0 + 64) = lo;
    }
}

/* ---- causal depthwise conv (d_conv=4) + SiLU -> [hi|lo] packed xc ---- */
__global__ __launch_bounds__(256) void conv_silu_kernel(
        const float* __restrict__ xi, const float* __restrict__ w,
        const float* __restrict__ b, unsigned short* __restrict__ xc_p) {
    size_t i = (size_t)blockIdx.x * 256 + threadIdx.x;
    int d = (int)(i & (D_INNER - 1));
    int tt = (int)(i >> 11);
    int s = tt & (SEQ - 1);
    float4 wv = ((const float4*)w)[d];
    float acc = b[d];
    if (s >= 3) acc += wv.x * xi[i - 3 * D_INNER];
    if (s >= 2) acc += wv.y * xi[i - 2 * D_INNER];
    if (s >= 1) acc += wv.z * xi[i - 1 * D_INNER];
    acc += wv.w * xi[i];
    float o = silu_f(acc);
    unsigned short hi = f2bf(o);
    unsigned short lo = f2bf(o - bf2f(hi));
    size_t o2 = (size_t)tt * (2 * D_INNER) + d;
    xc_p[o2]           = hi;
    xc_p[o2 + D_INNER] = lo;
}

/* ==== selective scan: thread-per-(b,d,chunk), states in registers.
   u reconstructed from packed xc (hi+lo). B/C rows are wave-uniform. ==== */

__global__ __launch_bounds__(256) void scanA_kernel(
        const unsigned short* __restrict__ xcp, const float* __restrict__ delta,
        const float* __restrict__ xdbl, const float* __restrict__ A_log,
        float* __restrict__ hpart, float* __restrict__ Pp) {
    const int bid = blockIdx.x;            /* 1024 blocks */
    const int b    = bid >> 9;
    const int c    = (bid >> 3) & 63;
    const int dblk = bid & 7;
    const int d    = (dblk << 8) + threadIdx.x;
    float adn[NSTATE];
    #pragma unroll
    for (int k = 0; k < 4; ++k) {
        float4 a = *(const float4*)(A_log + d * NSTATE + k * 4);
        adn[k*4+0] = -__expf(a.x); adn[k*4+1] = -__expf(a.y);
        adn[k*4+2] = -__expf(a.z); adn[k*4+3] = -__expf(a.w);
    }
    float h[NSTATE], P[NSTATE];
    #pragma unroll
    for (int n = 0; n < NSTATE; ++n) { h[n] = 0.f; P[n] = 1.f; }
    const int rowbase = b * SEQ + c * CHL;
    #pragma unroll 4
    for (int r = 0; r < CHL; ++r) {
        const int row = rowbase + r;
        const float* brow = xdbl + (size_t)row * XDBL + DT_RANK;  /* uniform addr */
        size_t o2 = (size_t)row * (2 * D_INNER) + d;
        float dl = delta[(size_t)row * D_INNER + d];
        float u  = bf2f(xcp[o2]) + bf2f(xcp[o2 + D_INNER]);
        float du = dl * u;
        #pragma unroll
        for (int n = 0; n < NSTATE; ++n) {
            float dA = __expf(dl * adn[n]);
            h[n] = fmaf(dA, h[n], du * brow[n]);
            P[n] *= dA;
        }
    }
    size_t base = (size_t)c * BDN + (size_t)(b * D_INNER + d) * NSTATE;
    #pragma unroll
    for (int k = 0; k < 4; ++k) {
        *(float4*)(hpart + base + k * 4) = make_float4(h[k*4], h[k*4+1], h[k*4+2], h[k*4+3]);
        *(float4*)(Pp    + base + k * 4) = make_float4(P[k*4], P[k*4+1], P[k*4+2], P[k*4+3]);
    }
}

__global__ __launch_bounds__(256) void scanB_kernel(
        const float* __restrict__ hpart, const float* __restrict__ Pp,
        float* __restrict__ hstart) {
    int idx = blockIdx.x * 256 + threadIdx.x;
    float h = 0.f;
    for (int c = 0; c < NCH; ++c) {
        hstart[(size_t)c * BDN + idx] = h;
        h = fmaf(Pp[(size_t)c * BDN + idx], h, hpart[(size_t)c * BDN + idx]);
    }
}

/* scanC: y_p aliases xcp (in-place over the packed-xc buffer).
   Safe: each (row,d) cell pair is owned by exactly one thread, and the
   writes data-depend on that thread's own reads of the same cells.
   ysum uses 4 accumulators to break the 16-deep FMA chain.              */
__global__ __launch_bounds__(256) void scanC_kernel(
        const unsigned short* xcp, const float* __restrict__ delta,
        const float* __restrict__ xdbl, const float* __restrict__ A_log,
        const float* __restrict__ Dp, const float* __restrict__ hstart,
        const float* __restrict__ res, unsigned short* y_p) {
    const int bid = blockIdx.x;            /* 1024 blocks */
    const int b    = bid >> 9;
    const int c    = (bid >> 3) & 63;
    const int dblk = bid & 7;
    const int d    = (dblk << 8) + threadIdx.x;
    float adn[NSTATE];
    #pragma unroll
    for (int k = 0; k < 4; ++k) {
        float4 a = *(const float4*)(A_log + d * NSTATE + k * 4);
        adn[k*4+0] = -__expf(a.x); adn[k*4+1] = -__expf(a.y);
        adn[k*4+2] = -__expf(a.z); adn[k*4+3] = -__expf(a.w);
    }
    const float Dd = Dp[d];
    float h[NSTATE];
    size_t base = (size_t)c * BDN + (size_t)(b * D_INNER + d) * NSTATE;
    #pragma unroll
    for (int k = 0; k < 4; ++k) {
        float4 hv = *(const float4*)(hstart + base + k * 4);
        h[k*4] = hv.x; h[k*4+1] = hv.y; h[k*4+2] = hv.z; h[k*4+3] = hv.w;
    }
    const int rowbase = b * SEQ + c * CHL;
    #pragma unroll 4
    for (int r = 0; r < CHL; ++r) {
        const int row = rowbase + r;
        const float* brow = xdbl + (size_t)row * XDBL + DT_RANK;       /* uniform */
        const float* crow = brow + NSTATE;                              /* uniform */
        size_t o2 = (size_t)row * (2 * D_INNER) + d;
        float dl = delta[(size_t)row * D_INNER + d];
        float u  = bf2f(xcp[o2]) + bf2f(xcp[o2 + D_INNER]);
        float du = dl * u;
        float ys[4];
        ys[0] = u * Dd; ys[1] = 0.f; ys[2] = 0.f; ys[3] = 0.f;
        #pragma unroll
        for (int n = 0; n < NSTATE; ++n) {
            float dA = __expf(dl * adn[n]);
            h[n] = fmaf(dA, h[n], du * brow[n]);
            ys[n & 3] = fmaf(h[n], crow[n], ys[n & 3]);
        }
        float ysum = (ys[0] + ys[1]) + (ys[2] + ys[3]);
        float rv = res[(size_t)row * D_INNER + d];
        float gv = ysum * silu_f(rv);
        unsigned short hi = f2bf(gv);
        unsigned short lo = f2bf(gv - bf2f(hi));
        y_p[o2]           = hi;
        y_p[o2 + D_INNER] = lo;
    }
}

extern "C" void kernel_launch(void* const* d_in, const int* in_sizes, int n_in,
                              void* d_out, int out_size, void* d_ws, size_t ws_size,
                              hipStream_t stream) {
    const float* x         = (const float*)d_in[0];
    const float* norm_w    = (const float*)d_in[1];
    const float* in_proj_w = (const float*)d_in[2];
    const float* conv_w    = (const float*)d_in[3];
    const float* conv_b    = (const float*)d_in[4];
    const float* x_proj_w  = (const float*)d_in[5];
    const float* dt_proj_w = (const float*)d_in[6];
    const float* dt_proj_b = (const float*)d_in[7];
    const float* A_log     = (const float*)d_in[8];
    const float* Dp        = (const float*)d_in[9];
    const float* out_proj_w= (const float*)d_in[10];
    float* out = (float*)d_out;
    float* ws  = (float*)d_ws;

    const size_t M8 = (size_t)T_TOK * D_INNER;           /* 8388608 */
    float* res   = ws;                                    /* 8M fl; dead after scanC */
    float* delta = res + M8;                              /* 8M fl; dead after scanC */
    float* xdbl  = delta + M8;                            /* 393216 fl */
    unsigned short* xn_p   = (unsigned short*)(xdbl + (size_t)T_TOK * XDBL);
    unsigned short* w_in_p = xn_p   + (size_t)4096 * 2048;   /* 4096x1024 sh */
    unsigned short* w_out_p= w_in_p + (size_t)4096 * 1024;   /* 1024x4096 sh */
    unsigned short* w_xp_p = w_out_p+ (size_t)1024 * 4096;   /* 96x4096 sh */
    unsigned short* w_dt_p = w_xp_p + (size_t)96 * 4096;     /* 2048x128 sh */
    unsigned short* xc_p   = w_dt_p + (size_t)2048 * 128;    /* 4096x4096 sh */
    unsigned short* dtp_p  = xc_p   + (size_t)4096 * 4096;   /* 4096x128 sh */
    float* xi    = (float*)(dtp_p + (size_t)4096 * 128);     /* 8M fl */
    /* scan buffers (each BDN*NCH = 4.19M fl):
       hpart = xi[0..4.19M)  (xi dead after conv)
       Pp    = xi[4.19M..8.38M)  (extends ws tail by ~0.38M fl)
       hstart aliases xn_p (+ spill into w_in_p), both dead after in_proj
       parts_x aliases delta region (dead until dt_proj writes it)       */
    float* hpart = xi;
    float* Pp    = xi + (size_t)BDN * NCH;
    float* hstart= (float*)xn_p;
    float* parts_x = delta;
    unsigned short* y_p = xc_p;                 /* in-place over packed xc */
    float* parts = ws;                          /* res+delta region: 16M fl */
    const size_t partStride = (size_t)T_TOK * HIDDEN;        /* 4194304 */

    /* weight packs */
    wpack_kernel<1><<<4096, 256, 0, stream>>>(in_proj_w,  w_in_p,  HIDDEN);
    wpack_kernel<2><<<2048, 256, 0, stream>>>(out_proj_w, w_out_p, D_INNER);
    wpack_kernel<2><<<192,  256, 0, stream>>>(x_proj_w,   w_xp_p,  D_INNER);
    wpack_kernel<2><<<128,  256, 0, stream>>>(dt_proj_w,  w_dt_p,  DT_RANK);

    /* RMSNorm + [hi|lo] pack */
    rmsnorm_pack_kernel<<<T_TOK, 256, 0, stream>>>(x, norm_w, xn_p);

    { /* in_proj (2-term): [4096,1024]@[4096,1024]^T -> xi | res */
        dim3 g(4096 / 128, T_TOK / 128, 1);
        mgemm_kernel<2, 0><<<g, 256, 0, stream>>>(xn_p, w_in_p, HIDDEN, HIDDEN,
                                                  4096, xi, res, D_INNER, D_INNER, 0, nullptr);
    }

    /* conv + SiLU -> [hi|lo] packed xc */
    conv_silu_kernel<<<(int)(M8 / 256), 256, 0, stream>>>(xi, conv_w, conv_b, xc_p);

    { /* x_proj (3-term, split-K=4, N padded 96->128): partials */
        dim3 g(1, T_TOK / 128, 4);
        mgemm_kernel<3, 2><<<g, 256, 0, stream>>>(xc_p, w_xp_p, D_INNER, D_INNER / 4,
                                                  96, parts_x, nullptr, 0, 128, 524288, nullptr);
    }
    reduceX_kernel<<<T_TOK * 24 / 256, 256, 0, stream>>>(parts_x, xdbl, dtp_p);

    { /* dt_proj (3-term) + bias + softplus -> delta */
        dim3 g(D_INNER / 128, T_TOK / 128, 1);
        mgemm_kernel<3, 3><<<g, 256, 0, stream>>>(dtp_p, w_dt_p, DT_RANK, DT_RANK,
                                                  D_INNER, delta, nullptr, 0, D_INNER, 0, dt_proj_b);
    }

    /* selective scan */
    scanA_kernel<<<BATCH * NCH * 8, 256, 0, stream>>>(xc_p, delta, xdbl, A_log, hpart, Pp);
    scanB_kernel<<<BDN / 256, 256, 0, stream>>>(hpart, Pp, hstart);
    scanC_kernel<<<BATCH * NCH * 8, 256, 0, stream>>>(xc_p, delta, xdbl, A_log, Dp, hstart, res, y_p);

    { /* out_proj (3-term, split-K=4): partials */
        dim3 g(HIDDEN / 128, T_TOK / 128, 4);
        mgemm_kernel<3, 2><<<g, 256, 0, stream>>>(y_p, w_out_p, D_INNER, D_INNER / 4,
                                                  HIDDEN, parts, nullptr, 0, HIDDEN, partStride, nullptr);
    }
    /* residual + reduce */
    reduce4_kernel<<<(int)(partStride / 4 / 256), 256, 0, stream>>>(parts, partStride, x, out);
}

// Round 8
// 312.724 us; speedup vs baseline: 4.1476x; 1.0750x over previous
//
#include <hip/hip_runtime.h>
#include <math.h>

#define HIDDEN   1024
#define D_INNER  2048
#define NSTATE   16
#define DT_RANK  64
#define BATCH    2
#define SEQ      2048
#define T_TOK    (BATCH * SEQ)            /* 4096 tokens */
#define XDBL     (DT_RANK + 2 * NSTATE)   /* 96 */
#define NCH      64                       /* scan chunks */
#define CHL      (SEQ / NCH)              /* 32 steps per chunk */
#define BDN      (BATCH * D_INNER * NSTATE) /* 65536 */

typedef float f32x4   __attribute__((ext_vector_type(4)));
typedef short bf16x8  __attribute__((ext_vector_type(8)));
typedef short short4v __attribute__((ext_vector_type(4)));

#define AS1 __attribute__((address_space(1)))
#define AS3 __attribute__((address_space(3)))
#define GLOAD(src, dst) __builtin_amdgcn_global_load_lds( \
    (const AS1 unsigned int*)(src), (AS3 unsigned int*)(dst), 16, 0, 0)

__device__ __forceinline__ float silu_f(float x) { return x / (1.0f + __expf(-x)); }
__device__ __forceinline__ float softplus_f(float x) {
    return fmaxf(x, 0.0f) + log1pf(__expf(-fabsf(x)));
}
__device__ __forceinline__ unsigned short f2bf(float x) {
    unsigned int u = __float_as_uint(x);
    u += 0x7fffu + ((u >> 16) & 1u);           /* RNE */
    return (unsigned short)(u >> 16);
}
__device__ __forceinline__ float bf2f(unsigned short h) {
    return __uint_as_float(((unsigned int)h) << 16);
}

/* ---- weight pack. SEGS=1: [hi] (stride K). SEGS=2: [hi|lo] (stride 2K). ---- */
template<int SEGS>
__global__ __launch_bounds__(256) void wpack_kernel(
        const float* __restrict__ w, unsigned short* __restrict__ wp, int K) {
    int i = blockIdx.x * 256 + threadIdx.x;
    int kq = K >> 2;
    int row = i / kq;
    int c = (i - row * kq) << 2;
    float4 v = *(const float4*)(w + (size_t)row * K + c);
    short4v hi, lo;
    hi.x = f2bf(v.x); hi.y = f2bf(v.y); hi.z = f2bf(v.z); hi.w = f2bf(v.w);
    lo.x = f2bf(v.x - bf2f(hi.x)); lo.y = f2bf(v.y - bf2f(hi.y));
    lo.z = f2bf(v.z - bf2f(hi.z)); lo.w = f2bf(v.w - bf2f(hi.w));
    size_t b0 = (size_t)row * (SEGS * K) + c;
    *(short4v*)(wp + b0) = hi;
    if (SEGS == 2) *(short4v*)(wp + b0 + K) = lo;
}

/* ---- RMSNorm + [hi|lo] act pack: x[row,1024] -> xn_p[row,2048] ---- */
__global__ __launch_bounds__(256) void rmsnorm_pack_kernel(
        const float* __restrict__ x, const float* __restrict__ w,
        unsigned short* __restrict__ xn_p) {
    int row = blockIdx.x;
    float4 v = ((const float4*)(x + (size_t)row * HIDDEN))[threadIdx.x];
    float ss = v.x*v.x + v.y*v.y + v.z*v.z + v.w*v.w;
    #pragma unroll
    for (int off = 32; off; off >>= 1) ss += __shfl_down(ss, off);
    __shared__ float wsum[4];
    if ((threadIdx.x & 63) == 0) wsum[threadIdx.x >> 6] = ss;
    __syncthreads();
    float scale = rsqrtf((wsum[0] + wsum[1] + wsum[2] + wsum[3]) / (float)HIDDEN + 1e-5f);
    float4 wv = ((const float4*)w)[threadIdx.x];
    float o0 = v.x * scale * wv.x, o1 = v.y * scale * wv.y;
    float o2 = v.z * scale * wv.z, o3 = v.w * scale * wv.w;
    short4v hi, lo;
    hi.x = f2bf(o0); hi.y = f2bf(o1); hi.z = f2bf(o2); hi.w = f2bf(o3);
    lo.x = f2bf(o0 - bf2f(hi.x)); lo.y = f2bf(o1 - bf2f(hi.y));
    lo.z = f2bf(o2 - bf2f(hi.z)); lo.w = f2bf(o3 - bf2f(hi.w));
    size_t b0 = (size_t)row * (2 * HIDDEN) + threadIdx.x * 4;
    *(short4v*)&xn_p[b0]          = hi;
    *(short4v*)&xn_p[b0 + HIDDEN] = lo;
}

/* ---- in_proj 2-term GEMM, 128x256 tile, LDS 64KB ----
   C[4096,4096] = (Ah+Al)[4096,1024] @ Wh[4096,1024]^T
   cols < 2048 -> xi ; cols >= 2048 -> res (block-uniform split)        */
__global__ __launch_bounds__(256, 2) void mgemm_in_kernel(
        const unsigned short* __restrict__ Ap,   /* [4096][2048] hi|lo */
        const unsigned short* __restrict__ Wp,   /* [4096][1024] hi    */
        float* __restrict__ C0, float* __restrict__ C1) {
    __shared__ short Ah[128 * 64];
    __shared__ short Al[128 * 64];
    __shared__ short Bh[256 * 64];
    const int t = threadIdx.x;
    const int w = t >> 6, l = t & 63;
    const int m0 = blockIdx.y * 128, n0 = blockIdx.x * 256;
    const int lrow = l & 15;
    f32x4 acc[8][4];
    #pragma unroll
    for (int m = 0; m < 8; ++m)
        #pragma unroll
        for (int n = 0; n < 4; ++n) {
            acc[m][n].x = 0.f; acc[m][n].y = 0.f; acc[m][n].z = 0.f; acc[m][n].w = 0.f;
        }
    const int srow8 = l >> 3;                       /* 0..7 */
    const int sc8   = (l & 7) ^ srow8;              /* pre-swizzled col8 */
    /* A staging: wave w covers rows [w*32, w*32+32), 4 instrs (8 rows each) */
    const unsigned short* ga = Ap + (size_t)(m0 + w * 32 + srow8) * 2048 + sc8 * 8;
    /* B staging: wave w covers rows [w*64, w*64+64), 8 instrs */
    const unsigned short* gb = Wp + (size_t)(n0 + w * 64 + srow8) * 1024 + sc8 * 8;
    for (int k0 = 0; k0 < 1024; k0 += 64) {
        __syncthreads();
        #pragma unroll
        for (int q = 0; q < 4; ++q) {
            const int ar = (w * 32 + q * 8) * 128;  /* byte offset */
            GLOAD(ga + k0 + (size_t)q * 8 * 2048,        (char*)Ah + ar);
            GLOAD(ga + 1024 + k0 + (size_t)q * 8 * 2048, (char*)Al + ar);
        }
        #pragma unroll
        for (int q = 0; q < 8; ++q)
            GLOAD(gb + k0 + (size_t)q * 8 * 1024, (char*)Bh + (w * 64 + q * 8) * 128);
        __syncthreads();
        #pragma unroll
        for (int kk = 0; kk < 2; ++kk) {
            const int slot = ((kk * 4 + (l >> 4)) ^ (l & 7)) * 8;
            bf16x8 bh[4];
            #pragma unroll
            for (int n = 0; n < 4; ++n)
                bh[n] = *(const bf16x8*)&Bh[(w * 64 + n * 16 + lrow) * 64 + slot];
            #pragma unroll
            for (int m = 0; m < 8; ++m) {
                bf16x8 ah = *(const bf16x8*)&Ah[(m * 16 + lrow) * 64 + slot];
                bf16x8 al = *(const bf16x8*)&Al[(m * 16 + lrow) * 64 + slot];
                #pragma unroll
                for (int n = 0; n < 4; ++n) {
                    acc[m][n] = __builtin_amdgcn_mfma_f32_16x16x32_bf16(
                        ah, bh[n], acc[m][n], 0, 0, 0);
                    acc[m][n] = __builtin_amdgcn_mfma_f32_16x16x32_bf16(
                        al, bh[n], acc[m][n], 0, 0, 0);
                }
            }
        }
    }
    /* whole block is on one side of the col-2048 boundary (n0 multiple of 256) */
    float* dst = (n0 < D_INNER) ? C0 : C1;
    const int cbase = (n0 < D_INNER) ? n0 : n0 - D_INNER;
    #pragma unroll
    for (int m = 0; m < 8; ++m) {
        #pragma unroll
        for (int n = 0; n < 4; ++n) {
            #pragma unroll
            for (int j = 0; j < 4; ++j) {
                int row = m0 + m * 16 + (l >> 4) * 4 + j;
                int col = cbase + w * 64 + n * 16 + (l & 15);
                dst[(size_t)row * D_INNER + col] = acc[m][n][j];
            }
        }
    }
}

/* ---- component-packed split-bf16 MFMA GEMM (128x128) ----
   TERMS=3: C = Ah·Wh + Ah·Wl + Al·Wh  (A [hi|lo] stride 2K, W [hi|lo] stride 2K)
   EPI 2: partial store to C0 + z*partStride
   EPI 3: softplus(v + bias[col]) -> C0                                   */
template<int TERMS, int EPI>
__global__ __launch_bounds__(256) void mgemm_kernel(
        const unsigned short* __restrict__ Ap, const unsigned short* __restrict__ Wp,
        int Klog, int klen, int brows, float* __restrict__ C0, float* __restrict__ C1,
        int splitN, int ldout, size_t partStride, const float* __restrict__ bias) {
    constexpr int NT = (TERMS == 3) ? 4 : 3;
    __shared__ short lds[NT * 128 * 64];
    short* Ah = lds;
    short* Al = lds + 128 * 64;
    short* Bh = lds + 2 * 128 * 64;
    short* Bl = lds + 3 * 128 * 64;
    const int t = threadIdx.x;
    const int w = t >> 6, l = t & 63;
    const int m0 = blockIdx.y * 128, n0 = blockIdx.x * 128;
    const int kbeg = blockIdx.z * klen;
    const int wr = (w >> 1) * 64, wc = (w & 1) * 64;
    const int lrow = l & 15;
    f32x4 acc[4][4];
    #pragma unroll
    for (int m = 0; m < 4; ++m)
        #pragma unroll
        for (int n = 0; n < 4; ++n) {
            acc[m][n].x = 0.f; acc[m][n].y = 0.f; acc[m][n].z = 0.f; acc[m][n].w = 0.f;
        }
    const int Asr = 2 * Klog;
    const int Wsr = (TERMS == 3) ? 2 * Klog : Klog;
    const int srow = w * 32 + (l >> 3);
    const int sc8  = (l & 7) ^ ((l >> 3) & 7);
    const int brow = min(n0 + srow, brows - 1);   /* clamp for padded-N */
    const unsigned short* ga = Ap + (size_t)(m0 + srow) * Asr + sc8 * 8;
    const unsigned short* gb = Wp + (size_t)brow * Wsr + sc8 * 8;
    for (int k0 = kbeg; k0 < kbeg + klen; k0 += 64) {
        __syncthreads();
        #pragma unroll
        for (int q = 0; q < 4; ++q) {
            const int doff = (w * 32 + q * 8) * 128;
            GLOAD(ga + k0 + (size_t)q * 8 * Asr,        (char*)Ah + doff);
            GLOAD(ga + Klog + k0 + (size_t)q * 8 * Asr, (char*)Al + doff);
            GLOAD(gb + k0 + (size_t)q * 8 * Wsr,        (char*)Bh + doff);
            if (TERMS == 3)
                GLOAD(gb + Klog + k0 + (size_t)q * 8 * Wsr, (char*)Bl + doff);
        }
        __syncthreads();
        #pragma unroll
        for (int kk = 0; kk < 2; ++kk) {
            const int slot = ((kk * 4 + (l >> 4)) ^ (l & 7)) * 8;
            bf16x8 ah[4], al[4], bh[4], bl[4];
            #pragma unroll
            for (int m = 0; m < 4; ++m) {
                ah[m] = *(const bf16x8*)&Ah[(wr + m * 16 + lrow) * 64 + slot];
                al[m] = *(const bf16x8*)&Al[(wr + m * 16 + lrow) * 64 + slot];
            }
            #pragma unroll
            for (int n = 0; n < 4; ++n) {
                bh[n] = *(const bf16x8*)&Bh[(wc + n * 16 + lrow) * 64 + slot];
                if (TERMS == 3)
                    bl[n] = *(const bf16x8*)&Bl[(wc + n * 16 + lrow) * 64 + slot];
            }
            #pragma unroll
            for (int m = 0; m < 4; ++m)
                #pragma unroll
                for (int n = 0; n < 4; ++n) {
                    acc[m][n] = __builtin_amdgcn_mfma_f32_16x16x32_bf16(
                        ah[m], bh[n], acc[m][n], 0, 0, 0);
                    acc[m][n] = __builtin_amdgcn_mfma_f32_16x16x32_bf16(
                        al[m], bh[n], acc[m][n], 0, 0, 0);
                    if (TERMS == 3)
                        acc[m][n] = __builtin_amdgcn_mfma_f32_16x16x32_bf16(
                            ah[m], bl[n], acc[m][n], 0, 0, 0);
                }
        }
    }
    float* dst = (EPI == 2) ? (C0 + blockIdx.z * partStride) : C0;
    #pragma unroll
    for (int m = 0; m < 4; ++m) {
        #pragma unroll
        for (int n = 0; n < 4; ++n) {
            #pragma unroll
            for (int j = 0; j < 4; ++j) {
                int row = m0 + wr + m * 16 + (l >> 4) * 4 + j;
                int col = n0 + wc + n * 16 + (l & 15);
                float v = acc[m][n][j];
                if (EPI == 2) {
                    dst[(size_t)row * ldout + col] = v;
                } else {
                    C0[(size_t)row * ldout + col] = softplus_f(v + bias[col]);
                }
            }
        }
    }
}

/* ---- reduce 2 split-K partials + residual x -> out (out_proj) ---- */
__global__ __launch_bounds__(256) void reduce2_kernel(
        const float* __restrict__ parts, size_t partStride,
        const float* __restrict__ x, float* __restrict__ out) {
    size_t i = (size_t)blockIdx.x * 256 + threadIdx.x;   /* float4 index */
    float4 a = ((const float4*)(parts))[i];
    float4 b = ((const float4*)(parts + partStride))[i];
    float4 xv = ((const float4*)x)[i];
    float4 o;
    o.x = a.x + b.x + xv.x;
    o.y = a.y + b.y + xv.y;
    o.z = a.z + b.z + xv.z;
    o.w = a.w + b.w + xv.w;
    ((float4*)out)[i] = o;
}

/* ---- reduce 8 x_proj partials -> xdbl fp32 [4096,96] + dtp_p [hi|lo] [4096,128] ---- */
__global__ __launch_bounds__(256) void reduceX_kernel(
        const float* __restrict__ parts, float* __restrict__ xdbl,
        unsigned short* __restrict__ dtp) {
    int i = blockIdx.x * 256 + threadIdx.x;      /* 4096*24 total */
    int row = i / 24;
    int c = (i - row * 24) * 4;
    float4 s = make_float4(0.f, 0.f, 0.f, 0.f);
    #pragma unroll
    for (int z = 0; z < 8; ++z) {
        float4 a = *(const float4*)(parts + (size_t)z * 524288 + (size_t)row * 128 + c);
        s.x += a.x; s.y += a.y; s.z += a.z; s.w += a.w;
    }
    *(float4*)(xdbl + (size_t)row * XDBL + c) = s;
    if (c < DT_RANK) {
        short4v hi, lo;
        hi.x = f2bf(s.x); hi.y = f2bf(s.y); hi.z = f2bf(s.z); hi.w = f2bf(s.w);
        lo.x = f2bf(s.x - bf2f(hi.x)); lo.y = f2bf(s.y - bf2f(hi.y));
        lo.z = f2bf(s.z - bf2f(hi.z)); lo.w = f2bf(s.w - bf2f(hi.w));
        size_t b0 = (size_t)row * 128 + c;
        *(short4v*)(dtp + b0)      = hi;
        *(short4v*)(dtp + b0 + 64) = lo;
    }
}

/* ---- causal depthwise conv (d_conv=4) + SiLU -> [hi|lo] packed xc ---- */
__global__ __launch_bounds__(256) void conv_silu_kernel(
        const float* __restrict__ xi, const float* __restrict__ w,
        const float* __restrict__ b, unsigned short* __restrict__ xc_p) {
    size_t i = (size_t)blockIdx.x * 256 + threadIdx.x;
    int d = (int)(i & (D_INNER - 1));
    int tt = (int)(i >> 11);
    int s = tt & (SEQ - 1);
    float4 wv = ((const float4*)w)[d];
    float acc = b[d];
    if (s >= 3) acc += wv.x * xi[i - 3 * D_INNER];
    if (s >= 2) acc += wv.y * xi[i - 2 * D_INNER];
    if (s >= 1) acc += wv.z * xi[i - 1 * D_INNER];
    acc += wv.w * xi[i];
    float o = silu_f(acc);
    unsigned short hi = f2bf(o);
    unsigned short lo = f2bf(o - bf2f(hi));
    size_t o2 = (size_t)tt * (2 * D_INNER) + d;
    xc_p[o2]           = hi;
    xc_p[o2 + D_INNER] = lo;
}

/* ==== selective scan: thread-per-(b,d,chunk), states in registers ==== */

__global__ __launch_bounds__(256) void scanA_kernel(
        const unsigned short* __restrict__ xcp, const float* __restrict__ delta,
        const float* __restrict__ xdbl, const float* __restrict__ A_log,
        float* __restrict__ hpart, float* __restrict__ Pp) {
    const int bid = blockIdx.x;            /* 1024 blocks */
    const int b    = bid >> 9;
    const int c    = (bid >> 3) & 63;
    const int dblk = bid & 7;
    const int d    = (dblk << 8) + threadIdx.x;
    float adn[NSTATE];
    #pragma unroll
    for (int k = 0; k < 4; ++k) {
        float4 a = *(const float4*)(A_log + d * NSTATE + k * 4);
        adn[k*4+0] = -__expf(a.x); adn[k*4+1] = -__expf(a.y);
        adn[k*4+2] = -__expf(a.z); adn[k*4+3] = -__expf(a.w);
    }
    float h[NSTATE], P[NSTATE];
    #pragma unroll
    for (int n = 0; n < NSTATE; ++n) { h[n] = 0.f; P[n] = 1.f; }
    const int rowbase = b * SEQ + c * CHL;
    #pragma unroll 4
    for (int r = 0; r < CHL; ++r) {
        const int row = rowbase + r;
        const float* brow = xdbl + (size_t)row * XDBL + DT_RANK;  /* uniform addr */
        size_t o2 = (size_t)row * (2 * D_INNER) + d;
        float dl = delta[(size_t)row * D_INNER + d];
        float u  = bf2f(xcp[o2]) + bf2f(xcp[o2 + D_INNER]);
        float du = dl * u;
        #pragma unroll
        for (int n = 0; n < NSTATE; ++n) {
            float dA = __expf(dl * adn[n]);
            h[n] = fmaf(dA, h[n], du * brow[n]);
            P[n] *= dA;
        }
    }
    size_t base = (size_t)c * BDN + (size_t)(b * D_INNER + d) * NSTATE;
    #pragma unroll
    for (int k = 0; k < 4; ++k) {
        *(float4*)(hpart + base + k * 4) = make_float4(h[k*4], h[k*4+1], h[k*4+2], h[k*4+3]);
        *(float4*)(Pp    + base + k * 4) = make_float4(P[k*4], P[k*4+1], P[k*4+2], P[k*4+3]);
    }
}

__global__ __launch_bounds__(256) void scanB_kernel(
        const float* __restrict__ hpart, const float* __restrict__ Pp,
        float* __restrict__ hstart) {
    int idx = blockIdx.x * 256 + threadIdx.x;
    float h = 0.f;
    for (int c = 0; c < NCH; ++c) {
        hstart[(size_t)c * BDN + idx] = h;
        h = fmaf(Pp[(size_t)c * BDN + idx], h, hpart[(size_t)c * BDN + idx]);
    }
}

/* scanC: y_p aliases xcp (in-place, per-cell exclusive ownership). */
__global__ __launch_bounds__(256) void scanC_kernel(
        const unsigned short* xcp, const float* __restrict__ delta,
        const float* __restrict__ xdbl, const float* __restrict__ A_log,
        const float* __restrict__ Dp, const float* __restrict__ hstart,
        const float* __restrict__ res, unsigned short* y_p) {
    const int bid = blockIdx.x;            /* 1024 blocks */
    const int b    = bid >> 9;
    const int c    = (bid >> 3) & 63;
    const int dblk = bid & 7;
    const int d    = (dblk << 8) + threadIdx.x;
    float adn[NSTATE];
    #pragma unroll
    for (int k = 0; k < 4; ++k) {
        float4 a = *(const float4*)(A_log + d * NSTATE + k * 4);
        adn[k*4+0] = -__expf(a.x); adn[k*4+1] = -__expf(a.y);
        adn[k*4+2] = -__expf(a.z); adn[k*4+3] = -__expf(a.w);
    }
    const float Dd = Dp[d];
    float h[NSTATE];
    size_t base = (size_t)c * BDN + (size_t)(b * D_INNER + d) * NSTATE;
    #pragma unroll
    for (int k = 0; k < 4; ++k) {
        float4 hv = *(const float4*)(hstart + base + k * 4);
        h[k*4] = hv.x; h[k*4+1] = hv.y; h[k*4+2] = hv.z; h[k*4+3] = hv.w;
    }
    const int rowbase = b * SEQ + c * CHL;
    #pragma unroll 4
    for (int r = 0; r < CHL; ++r) {
        const int row = rowbase + r;
        const float* brow = xdbl + (size_t)row * XDBL + DT_RANK;       /* uniform */
        const float* crow = brow + NSTATE;                              /* uniform */
        size_t o2 = (size_t)row * (2 * D_INNER) + d;
        float dl = delta[(size_t)row * D_INNER + d];
        float u  = bf2f(xcp[o2]) + bf2f(xcp[o2 + D_INNER]);
        float du = dl * u;
        float ys[4];
        ys[0] = u * Dd; ys[1] = 0.f; ys[2] = 0.f; ys[3] = 0.f;
        #pragma unroll
        for (int n = 0; n < NSTATE; ++n) {
            float dA = __expf(dl * adn[n]);
            h[n] = fmaf(dA, h[n], du * brow[n]);
            ys[n & 3] = fmaf(h[n], crow[n], ys[n & 3]);
        }
        float ysum = (ys[0] + ys[1]) + (ys[2] + ys[3]);
        float rv = res[(size_t)row * D_INNER + d];
        float gv = ysum * silu_f(rv);
        unsigned short hi = f2bf(gv);
        unsigned short lo = f2bf(gv - bf2f(hi));
        y_p[o2]           = hi;
        y_p[o2 + D_INNER] = lo;
    }
}

extern "C" void kernel_launch(void* const* d_in, const int* in_sizes, int n_in,
                              void* d_out, int out_size, void* d_ws, size_t ws_size,
                              hipStream_t stream) {
    const float* x         = (const float*)d_in[0];
    const float* norm_w    = (const float*)d_in[1];
    const float* in_proj_w = (const float*)d_in[2];
    const float* conv_w    = (const float*)d_in[3];
    const float* conv_b    = (const float*)d_in[4];
    const float* x_proj_w  = (const float*)d_in[5];
    const float* dt_proj_w = (const float*)d_in[6];
    const float* dt_proj_b = (const float*)d_in[7];
    const float* A_log     = (const float*)d_in[8];
    const float* Dp        = (const float*)d_in[9];
    const float* out_proj_w= (const float*)d_in[10];
    float* out = (float*)d_out;
    float* ws  = (float*)d_ws;

    const size_t M8 = (size_t)T_TOK * D_INNER;           /* 8388608 */
    float* res   = ws;                                    /* 8M fl; dead after scanC */
    float* delta = res + M8;                              /* 8M fl; dead after scanC */
    float* xdbl  = delta + M8;                            /* 393216 fl */
    unsigned short* xn_p   = (unsigned short*)(xdbl + (size_t)T_TOK * XDBL);
    unsigned short* w_in_p = xn_p   + (size_t)4096 * 2048;   /* 4096x1024 sh */
    unsigned short* w_out_p= w_in_p + (size_t)4096 * 1024;   /* 1024x4096 sh */
    unsigned short* w_xp_p = w_out_p+ (size_t)1024 * 4096;   /* 96x4096 sh */
    unsigned short* w_dt_p = w_xp_p + (size_t)96 * 4096;     /* 2048x128 sh */
    unsigned short* xc_p   = w_dt_p + (size_t)2048 * 128;    /* 4096x4096 sh */
    unsigned short* dtp_p  = xc_p   + (size_t)4096 * 4096;   /* 4096x128 sh */
    float* xi    = (float*)(dtp_p + (size_t)4096 * 128);     /* 8M fl */
    float* hpart = xi;                          /* xi dead after conv */
    float* Pp    = xi + (size_t)BDN * NCH;
    float* hstart= (float*)xn_p;                /* 4.19M fl, dead after in_proj */
    float* parts_x = delta;                     /* 8x524288 fl, pre-dt_proj */
    unsigned short* y_p = xc_p;                 /* in-place over packed xc */
    float* parts = ws;                          /* res+delta region */
    const size_t partStride = (size_t)T_TOK * HIDDEN;        /* 4194304 */

    /* weight packs */
    wpack_kernel<1><<<4096, 256, 0, stream>>>(in_proj_w,  w_in_p,  HIDDEN);
    wpack_kernel<2><<<2048, 256, 0, stream>>>(out_proj_w, w_out_p, D_INNER);
    wpack_kernel<2><<<192,  256, 0, stream>>>(x_proj_w,   w_xp_p,  D_INNER);
    wpack_kernel<2><<<128,  256, 0, stream>>>(dt_proj_w,  w_dt_p,  DT_RANK);

    /* RMSNorm + [hi|lo] pack */
    rmsnorm_pack_kernel<<<T_TOK, 256, 0, stream>>>(x, norm_w, xn_p);

    { /* in_proj (2-term, 128x256 tile): -> xi | res */
        dim3 g(4096 / 256, T_TOK / 128, 1);
        mgemm_in_kernel<<<g, 256, 0, stream>>>(xn_p, w_in_p, xi, res);
    }

    /* conv + SiLU -> [hi|lo] packed xc */
    conv_silu_kernel<<<(int)(M8 / 256), 256, 0, stream>>>(xi, conv_w, conv_b, xc_p);

    { /* x_proj (3-term, split-K=8, N padded 96->128): partials */
        dim3 g(1, T_TOK / 128, 8);
        mgemm_kernel<3, 2><<<g, 256, 0, stream>>>(xc_p, w_xp_p, D_INNER, D_INNER / 8,
                                                  96, parts_x, nullptr, 0, 128, 524288, nullptr);
    }
    reduceX_kernel<<<T_TOK * 24 / 256, 256, 0, stream>>>(parts_x, xdbl, dtp_p);

    { /* dt_proj (3-term) + bias + softplus -> delta */
        dim3 g(D_INNER / 128, T_TOK / 128, 1);
        mgemm_kernel<3, 3><<<g, 256, 0, stream>>>(dtp_p, w_dt_p, DT_RANK, DT_RANK,
                                                  D_INNER, delta, nullptr, 0, D_INNER, 0, dt_proj_b);
    }

    /* selective scan */
    scanA_kernel<<<BATCH * NCH * 8, 256, 0, stream>>>(xc_p, delta, xdbl, A_log, hpart, Pp);
    scanB_kernel<<<BDN / 256, 256, 0, stream>>>(hpart, Pp, hstart);
    scanC_kernel<<<BATCH * NCH * 8, 256, 0, stream>>>(xc_p, delta, xdbl, A_log, Dp, hstart, res, y_p);

    { /* out_proj (3-term, split-K=2): partials */
        dim3 g(HIDDEN / 128, T_TOK / 128, 2);
        mgemm_kernel<3, 2><<<g, 256, 0, stream>>>(y_p, w_out_p, D_INNER, D_INNER / 2,
                                                  HIDDEN, parts, nullptr, 0, HIDDEN, partStride, nullptr);
    }
    /* residual + reduce */
    reduce2_kernel<<<(int)(partStride / 4 / 256), 256, 0, stream>>>(parts, partStride, x, out);
}